// Round 16
// baseline (162.992 us; speedup 1.0000x reference)
//
#include <hip/hip_runtime.h>
#include <math.h>

#define NH 16
#define HD 64

typedef unsigned short u16;
typedef unsigned int   u32;
using bf16x8 = __attribute__((ext_vector_type(8))) short;
using f32x4  = __attribute__((ext_vector_type(4))) float;
using u16x8  = __attribute__((ext_vector_type(8))) unsigned short;
using u16x4  = __attribute__((ext_vector_type(4))) unsigned short;
using u32x2  = __attribute__((ext_vector_type(2))) unsigned int;

__device__ __forceinline__ u16 f2bf(float x) {
    u32 u = __float_as_uint(x);
    u32 r = (u + 0x7FFFu + ((u >> 16) & 1u)) >> 16;
    return (u16)r;
}
__device__ __forceinline__ float bf2f(u16 h) { return __uint_as_float(((u32)h) << 16); }

#define GLDS16(src, dst) __builtin_amdgcn_global_load_lds( \
    (const __attribute__((address_space(1))) void*)(src),  \
    (__attribute__((address_space(3))) void*)(dst), 16, 0, 0)

#define LDS_OFF(p) ((u32)(uintptr_t)(__attribute__((address_space(3))) void*)(p))
#define DSREAD(d, a) asm volatile("ds_read_b128 %0, %1" : "=v"(d) : "v"(a))

#define MEMFENCE asm volatile("" ::: "memory")
#define BARMID { MEMFENCE; __builtin_amdgcn_s_barrier(); \
                 asm volatile("s_waitcnt lgkmcnt(0)" ::: "memory"); \
                 __builtin_amdgcn_sched_barrier(0); }
#define BAREND { MEMFENCE; __builtin_amdgcn_s_barrier(); MEMFENCE; }
#define VMW(n) asm volatile("s_waitcnt vmcnt(" #n ")" ::: "memory")

// ---------------------------------------------------------------------------
// x [8192][1024] f32 -> xt [8192][1024] bf16 (hi only)
__global__ __launch_bounds__(256) void convert_x(const float* __restrict__ x,
                                                 u16* __restrict__ xt) {
    int t = blockIdx.x * 256 + threadIdx.x;
    int m = t >> 7;
    int k = (t & 127) * 8;
    const float4* src = (const float4*)(x + (size_t)m * 1024 + k);
    float4 v0 = src[0], v1 = src[1];
    float vs[8] = {v0.x, v0.y, v0.z, v0.w, v1.x, v1.y, v1.z, v1.w};
    u16x8 hv;
    #pragma unroll
    for (int j = 0; j < 8; j++) hv[j] = f2bf(vs[j]);
    *(u16x8*)(xt + (size_t)m * 1024 + k) = hv;
}

// ---------------------------------------------------------------------------
// Wqkv [1024][3072] f32 -> transposed hi:
//   cols 0..2047   (Q,K): wqk [2048][1024]
//   cols 2048..3071 (V) : wv  [1024][1024]
__global__ __launch_bounds__(256) void conv_w(const float* __restrict__ W,
                                              u16* __restrict__ wqk,
                                              u16* __restrict__ wv) {
    __shared__ float Ts[32][33];
    const int N = 3072;
    int k0 = blockIdx.y * 32, n0 = blockIdx.x * 32;
    int t = threadIdx.x;
    int r = t >> 3, c4 = (t & 7) * 4;
    float4 v = *(const float4*)(W + (size_t)(k0 + r) * N + n0 + c4);
    Ts[r][c4] = v.x; Ts[r][c4 + 1] = v.y; Ts[r][c4 + 2] = v.z; Ts[r][c4 + 3] = v.w;
    __syncthreads();
    int nl = t >> 3, kl = (t & 7) * 4;
    u16x4 hv;
    #pragma unroll
    for (int j = 0; j < 4; j++) hv[j] = f2bf(Ts[kl + j][nl]);
    int col = n0 + nl;
    if (col < 2048) {
        *(u16x4*)&wqk[(size_t)col * 1024 + k0 + kl] = hv;
    } else {
        *(u16x4*)&wv[(size_t)(col - 2048) * 1024 + k0 + kl] = hv;
    }
}

// ---------------------------------------------------------------------------
// Wout [1024][1024] f32 -> Wt [1024][1024] bf16 hi (transposed)
__global__ __launch_bounds__(256) void conv_wout(const float* __restrict__ W,
                                                 u16* __restrict__ Wt) {
    __shared__ float Ts[32][33];
    const int N = 1024;
    int k0 = blockIdx.y * 32, n0 = blockIdx.x * 32;
    int t = threadIdx.x;
    int r = t >> 3, c4 = (t & 7) * 4;
    float4 v = *(const float4*)(W + (size_t)(k0 + r) * N + n0 + c4);
    Ts[r][c4] = v.x; Ts[r][c4 + 1] = v.y; Ts[r][c4 + 2] = v.z; Ts[r][c4 + 3] = v.w;
    __syncthreads();
    int nl = t >> 3, kl = (t & 7) * 4;
    u16x4 hv;
    #pragma unroll
    for (int j = 0; j < 4; j++) hv[j] = f2bf(Ts[kl + j][nl]);
    *(u16x4*)&Wt[(size_t)(n0 + nl) * 1024 + k0 + kl] = hv;
}

// ---------------------------------------------------------------------------
// 256x256 8-phase GEMM: Q,K projection (N=2048 -> grid exactly 256, Kp=1024).
// Epilogue: Q pre-scaled by (1/8)*log2(e) for exp2-based softmax; K plain.
__global__ __launch_bounds__(512, 2)
void gemm_qk_8ph(const u16* __restrict__ A, const u16* __restrict__ Bt,
                 u16* __restrict__ Qh, u16* __restrict__ Kh,
                 int Kp, int nbx) {
    __shared__ char LDS[131072];
    char* ldsA = LDS;
    char* ldsB = LDS + 65536;
    const u32 ldsAoff = LDS_OFF(ldsA);
    const u32 ldsBoff = ldsAoff + 65536;

    const int tid = threadIdx.x, lane = tid & 63, w = tid >> 6;
    const int wr = w >> 2, wc = w & 3;
    const int l15 = lane & 15;
    const int khb = (lane >> 4) << 4;
    const int lswz = (l15 & 7) << 4;
    const int Kp2 = Kp * 2;

    const int cpx = (int)gridDim.x >> 3;
    const int wg  = ((int)blockIdx.x & 7) * cpx + ((int)blockIdx.x >> 3);
    const int m0 = (wg / nbx) * 256, n0 = (wg % nbx) * 256;

    const int tp = tid >> 3;
    const int sw = ((tid & 7) * 16) ^ ((tp & 7) << 4);
    const int nA = ((tp >> 5) << 6) + (tp & 31);

    const char* Agb = (const char*)A  + (size_t)m0 * Kp2;
    const char* Bgb = (const char*)Bt + (size_t)n0 * Kp2;

#define STAGE_A(t, h, buf) { \
    const char* s_ = Agb + (t) * 128 + ((h) * 64 + tp) * Kp2 + sw; \
    char* d_ = ldsA + (buf) * 32768 + (h) * 16384 + (w << 10); \
    GLDS16(s_, d_); GLDS16(s_ + (size_t)128 * Kp2, d_ + 8192); }
#define STAGE_B(t, h, buf) { \
    const char* s_ = Bgb + (t) * 128 + (nA + (h) * 32) * Kp2 + sw; \
    char* d_ = ldsB + (buf) * 32768 + (h) * 16384 + (w << 10); \
    GLDS16(s_, d_); GLDS16(s_ + (size_t)128 * Kp2, d_ + 8192); }

    bf16x8 Af[4][2], Bf[2][2];

#define LOADA(buf, mh) { \
    _Pragma("unroll") \
    for (int mi = 0; mi < 4; ++mi) { \
        u32 rb_ = ldsAoff + (buf) * 32768 + (mh) * 16384 \
                + (u32)((wr * 64 + mi * 16 + l15) * 128); \
        DSREAD(Af[mi][0], rb_ + (u32)((khb) ^ lswz)); \
        DSREAD(Af[mi][1], rb_ + (u32)((64 + khb) ^ lswz)); \
    } }
#define LOADB(buf, nh) { \
    _Pragma("unroll") \
    for (int ni = 0; ni < 2; ++ni) { \
        u32 rb_ = ldsBoff + (buf) * 32768 + (nh) * 16384 \
                + (u32)((wc * 32 + ni * 16 + l15) * 128); \
        DSREAD(Bf[ni][0], rb_ + (u32)((khb) ^ lswz)); \
        DSREAD(Bf[ni][1], rb_ + (u32)((64 + khb) ^ lswz)); \
    } }
#define MM(mh, nh) { \
    __builtin_amdgcn_s_setprio(1); \
    _Pragma("unroll") \
    for (int kk = 0; kk < 2; ++kk) \
        _Pragma("unroll") \
        for (int mi = 0; mi < 4; ++mi) \
            _Pragma("unroll") \
            for (int ni = 0; ni < 2; ++ni) \
                acc[(mh) * 4 + mi][(nh) * 2 + ni] = \
                    __builtin_amdgcn_mfma_f32_16x16x32_bf16( \
                        Af[mi][kk], Bf[ni][kk], acc[(mh) * 4 + mi][(nh) * 2 + ni], 0, 0, 0); \
    __builtin_amdgcn_s_setprio(0); }

    f32x4 acc[8][4];
    #pragma unroll
    for (int i = 0; i < 8; i++)
        #pragma unroll
        for (int j = 0; j < 4; j++)
            acc[i][j] = f32x4{0.f, 0.f, 0.f, 0.f};

    const int NT = Kp >> 6;
    const int NITER = NT / 2 - 1;

    STAGE_B(0, 0, 0); STAGE_A(0, 1, 0); STAGE_B(0, 1, 0); STAGE_A(0, 0, 0);
    STAGE_B(1, 0, 1); STAGE_A(1, 1, 1); STAGE_B(1, 1, 1);
    VMW(6);
    MEMFENCE; __builtin_amdgcn_s_barrier(); MEMFENCE;

    for (int it = 0; it < NITER; ++it) {
        const int t = 2 * it;
        LOADA(0, 0); LOADB(0, 0); STAGE_A(t + 1, 0, 1);
        BARMID; MM(0, 0); BAREND;
        LOADA(0, 1); STAGE_B(t + 2, 0, 0);
        BARMID; MM(1, 0); BAREND;
        LOADB(0, 1); STAGE_A(t + 2, 1, 0);
        BARMID; MM(1, 1); BAREND;
        LOADA(0, 0); STAGE_B(t + 2, 1, 0); VMW(6);
        BARMID; MM(0, 1); BAREND;
        LOADA(1, 0); LOADB(1, 0); STAGE_A(t + 2, 0, 0);
        BARMID; MM(0, 0); BAREND;
        LOADA(1, 1); STAGE_B(t + 3, 0, 1);
        BARMID; MM(1, 0); BAREND;
        LOADB(1, 1); STAGE_A(t + 3, 1, 1);
        BARMID; MM(1, 1); BAREND;
        LOADA(1, 0); STAGE_B(t + 3, 1, 1); VMW(6);
        BARMID; MM(0, 1); BAREND;
    }

    LOADA(0, 0); LOADB(0, 0); STAGE_A(NT - 1, 0, 1);
    BARMID; MM(0, 0); BAREND;
    LOADA(0, 1);
    BARMID; MM(1, 0); BAREND;
    LOADB(0, 1);
    BARMID; MM(1, 1); BAREND;
    LOADA(0, 0); VMW(0);
    BARMID; MM(0, 1); BAREND;
    LOADA(1, 0); LOADB(1, 0);
    BARMID; MM(0, 0); BAREND;
    LOADA(1, 1);
    BARMID; MM(1, 0); BAREND;
    LOADB(1, 1);
    BARMID; MM(1, 1); BAREND;
    LOADA(1, 0);
    BARMID; MM(0, 1); BAREND;

    const int sel = n0 >> 10;   // 0 = Q, 1 = K
    u16* dst = (sel == 0) ? Qh : Kh;
    // Q scale folds 1/sqrt(64) and log2(e) (softmax uses exp2)
    const float sc = (sel == 0) ? 0.125f * 1.4426950408889634f : 1.0f;
    #pragma unroll
    for (int mh = 0; mh < 2; ++mh)
        #pragma unroll
        for (int mi = 0; mi < 4; ++mi)
            #pragma unroll
            for (int nh = 0; nh < 2; ++nh)
                #pragma unroll
                for (int ni = 0; ni < 2; ++ni) {
                    f32x4 a = acc[mh * 4 + mi][nh * 2 + ni];
                    int col = n0 + wc * 64 + nh * 32 + ni * 16 + l15;
                    int within = col & 1023;
                    int hh = within >> 6, d = within & 63;
                    int rowb = m0 + wr * 128 + mh * 64 + mi * 16 + (lane >> 4) * 4;
                    int bb = rowb >> 10, n = rowb & 1023;
                    size_t hn = (size_t)(bb * NH + hh) * 1024 + n;
                    #pragma unroll
                    for (int reg = 0; reg < 4; reg++)
                        dst[(hn + reg) * 64 + d] = f2bf(a[reg] * sc);
                }
#undef STAGE_A
#undef STAGE_B
#undef LOADA
#undef LOADB
#undef MM
}

// ---------------------------------------------------------------------------
// 128x128 bf16 GEMM, m97 structure, strided A/B (lda/ldb in elements).
// MODE 0: C f32 [M][N].  MODE 2: V write transposed -> Vtr [head][64][1024].
template<int MODE>
__global__ __launch_bounds__(256, 2)
void gemm_bf16(const u16* __restrict__ A, int lda,
               const u16* __restrict__ Bt, int ldb, int Kloop,
               float* __restrict__ C, u16* __restrict__ Vtr, int N, int nbx) {
    __shared__ u16 As[128 * 64];
    __shared__ u16 Bs[128 * 64];
    const char* AsC = (const char*)As;
    const char* BsC = (const char*)Bs;

    const int t = threadIdx.x;
    const int lane = t & 63, w = t >> 6;

    const int cpx = (int)gridDim.x >> 3;
    const int wg  = (blockIdx.x & 7) * cpx + (blockIdx.x >> 3);
    const int m0 = (wg / nbx) * 128, n0 = (wg % nbx) * 128;

    const int l15 = lane & 15;
    const int g16 = (lane >> 4) << 4;
    const int swz = (l15 & 7) << 4;

    const char* srcA[4];
    const char* srcB[4];
    char* dstA[4];
    char* dstB[4];
    #pragma unroll
    for (int i = 0; i < 4; i++) {
        int s = (w * 4 + i) * 64 + lane;
        int row  = (s * 16) >> 7;
        int colb = (s * 16) & 127;
        int scol = colb ^ ((row & 7) << 4);
        srcA[i] = (const char*)A  + ((size_t)(m0 + row) * lda) * 2 + scol;
        srcB[i] = (const char*)Bt + ((size_t)(n0 + row) * ldb) * 2 + scol;
        dstA[i] = (char*)As + (w * 4 + i) * 1024;
        dstB[i] = (char*)Bs + (w * 4 + i) * 1024;
    }

    const int wm = (w >> 1) * 64, wn = (w & 1) * 64;
    int rA[4], rB[4];
    #pragma unroll
    for (int i = 0; i < 4; i++) {
        rA[i] = (wm + i * 16 + l15) * 128;
        rB[i] = (wn + i * 16 + l15) * 128;
    }

    f32x4 acc[4][4];
    #pragma unroll
    for (int i = 0; i < 4; i++)
        #pragma unroll
        for (int j = 0; j < 4; j++)
            acc[i][j] = f32x4{0.f, 0.f, 0.f, 0.f};

    for (int k0 = 0; k0 < Kloop; k0 += 64) {
        __syncthreads();
        #pragma unroll
        for (int i = 0; i < 4; i++) {
            GLDS16(srcA[i], dstA[i]);
            GLDS16(srcB[i], dstB[i]);
            srcA[i] += 128;
            srcB[i] += 128;
        }
        __syncthreads();
        #pragma unroll
        for (int kb = 0; kb < 2; kb++) {
            const int csw = ((kb << 6) | g16) ^ swz;
            bf16x8 af[4], bfr[4];
            #pragma unroll
            for (int mi = 0; mi < 4; mi++) af[mi]  = *(const bf16x8*)(AsC + rA[mi] + csw);
            #pragma unroll
            for (int ni = 0; ni < 4; ni++) bfr[ni] = *(const bf16x8*)(BsC + rB[ni] + csw);
            #pragma unroll
            for (int mi = 0; mi < 4; mi++)
                #pragma unroll
                for (int ni = 0; ni < 4; ni++)
                    acc[mi][ni] = __builtin_amdgcn_mfma_f32_16x16x32_bf16(
                        af[mi], bfr[ni], acc[mi][ni], 0, 0, 0);
        }
    }

    if (MODE == 0) {
        #pragma unroll
        for (int mi = 0; mi < 4; mi++) {
            int rowb = m0 + wm + mi * 16 + (lane >> 4) * 4;
            #pragma unroll
            for (int ni = 0; ni < 4; ni++) {
                int col = n0 + wn + ni * 16 + l15;
                #pragma unroll
                for (int reg = 0; reg < 4; reg++)
                    C[(size_t)(rowb + reg) * N + col] = acc[mi][ni][reg];
            }
        }
    } else {
        // V: write transposed [head][d][key]
        #pragma unroll
        for (int ni = 0; ni < 4; ni++) {
            int col = n0 + wn + ni * 16 + l15;      // 0..1023
            int hh = col >> 6, d = col & 63;
            #pragma unroll
            for (int mi = 0; mi < 4; mi++) {
                int rowb = m0 + wm + mi * 16 + (lane >> 4) * 4;
                int bb = rowb >> 10, n = rowb & 1023;
                u16x4 vv;
                #pragma unroll
                for (int reg = 0; reg < 4; reg++)
                    vv[reg] = f2bf(acc[mi][ni][reg]);
                *(u16x4*)&Vtr[((size_t)(bb * NH + hh) * 64 + d) * 1024 + n] = vv;
            }
        }
    }
}

// ---------------------------------------------------------------------------
// Flash attention, swapped-QK^T (T12). Q [head][1024][64] (pre-scaled by
// 0.125*log2e), K [head][1024][64], Vt [head][64][1024]. Double-buffered K/V
// via global_load_lds (T3-minimum): stage buf^1 at top, compute buf, ONE
// __syncthreads per kt (drains gloads + LDS). Softmax via exp2 (v_exp_f32).
// P layout: R13-proven 144B-stride rows, short-typed b64 stores + fence.
__global__ __launch_bounds__(256, 3)
void attn_mfma(const u16* __restrict__ Qh, const u16* __restrict__ Kh,
               const u16* __restrict__ Vt, u16* __restrict__ AO) {
    __shared__ u16 Ks[2][64 * 64];
    __shared__ u16 Vs[2][64 * 64];
    __shared__ u16 Ps[4][16 * 72];

    const int t = threadIdx.x, lane = t & 63, w = t >> 6;

    const int orig = blockIdx.x;
    const int xcd = orig & 7, slot = orig >> 3;
    const int head_lin = xcd * 16 + (slot >> 4);
    const int qt = slot & 15;
    const int b = head_lin >> 4, h = head_lin & 15;
    const size_t head = (size_t)head_lin;

    const char* Qg = (const char*)(Qh + head * 1024 * 64) + qt * 64 * 128;
    const char* Kg = (const char*)(Kh + head * 1024 * 64);
    const char* Vg = (const char*)(Vt + head * 64 * 1024);
    char* KsC = (char*)Ks;
    char* VsC = (char*)Vs;
    char* PsC = (char*)(&Ps[w][0]);

    const int l15 = lane & 15;
    const int g16 = (lane >> 4) << 4;
    const int g8  = (lane >> 4) << 3;

    // staging geometry: thread stages chunks (w*2+i) of each 8KB tile
    int koff[2], vgoff[2], ldst[2];
    #pragma unroll
    for (int i = 0; i < 2; i++) {
        int c = (w * 2 + i) * 64 + lane;
        int row = c >> 3, colb = (c & 7) * 16;
        int soff = colb ^ ((row & 7) << 4);
        koff[i]  = row * 128 + soff;     // K: [key][64 d] rows, + kt*8192
        vgoff[i] = row * 2048 + soff;    // V: [d][1024 key] rows, + kt*128
        ldst[i]  = (w * 2 + i) * 1024;   // linear LDS chunk
    }

#define STAGE_KV(kt, buf) { \
    _Pragma("unroll") \
    for (int i = 0; i < 2; i++) { \
        GLDS16(Kg + (kt) * 8192 + koff[i], KsC + (buf) * 8192 + ldst[i]); \
        GLDS16(Vg + (kt) * 128  + vgoff[i], VsC + (buf) * 8192 + ldst[i]); \
    } }

    // Q fragments from global (row-major [64 q][64 d], 128B rows)
    const int qrow = w * 16 + l15;
    bf16x8 qf[2];
    #pragma unroll
    for (int kk = 0; kk < 2; kk++)
        qf[kk] = *(const bf16x8*)(Qg + qrow * 128 + kk * 64 + g16);

    float lp = 0.f;                     // partial softmax denom for q = l15
    f32x4 acc_o[4];
    #pragma unroll
    for (int i = 0; i < 4; i++) acc_o[i] = f32x4{0.f, 0.f, 0.f, 0.f};

    STAGE_KV(0, 0);
    __syncthreads();                    // drains gloads (vmcnt) + barrier

    for (int kt = 0; kt < 16; kt++) {
        const int cur = kt & 1;
        if (kt < 15) STAGE_KV(kt + 1, cur ^ 1);

        // S^T = K Q^T (swapped operands): lane holds S^T[k=c*16+4g+reg][q=l15]
        f32x4 sacc[4];
        #pragma unroll
        for (int c = 0; c < 4; c++) sacc[c] = f32x4{0.f, 0.f, 0.f, 0.f};
        __builtin_amdgcn_s_setprio(1);
        #pragma unroll
        for (int kk = 0; kk < 2; kk++) {
            int csw = ((kk * 64) | g16) ^ ((l15 & 7) << 4);
            #pragma unroll
            for (int c = 0; c < 4; c++) {
                bf16x8 bk = *(const bf16x8*)(KsC + cur * 8192 + (c * 16 + l15) * 128 + csw);
                sacc[c] = __builtin_amdgcn_mfma_f32_16x16x32_bf16(bk, qf[kk], sacc[c], 0, 0, 0);
            }
        }
        __builtin_amdgcn_s_setprio(0);

        // P = exp2(S) (Q pre-scaled by log2e); lane-partial l; cvt_pk pack ->
        // one short-typed b64 store per block (144B-stride rows)
        {
            char* pb = PsC + l15 * 144 + g8;
            #pragma unroll
            for (int c = 0; c < 4; c++) {
                float p0 = exp2f(sacc[c][0]);
                float p1 = exp2f(sacc[c][1]);
                float p2 = exp2f(sacc[c][2]);
                float p3 = exp2f(sacc[c][3]);
                lp += (p0 + p1) + (p2 + p3);
                u32 w0, w1;
                asm("v_cvt_pk_bf16_f32 %0, %1, %2" : "=v"(w0) : "v"(p0), "v"(p1));
                asm("v_cvt_pk_bf16_f32 %0, %1, %2" : "=v"(w1) : "v"(p2), "v"(p3));
                u16x4 pk = __builtin_bit_cast(u16x4, u32x2{w0, w1});
                *(u16x4*)(pb + c * 32) = pk;
            }
        }
        // pin ordering: P writes complete before PV reads (compiler + HW)
        MEMFENCE;
        asm volatile("s_waitcnt lgkmcnt(0)" ::: "memory");
        __builtin_amdgcn_sched_barrier(0);

        // O += P @ V  (P read: row l15 at 144B stride)
        __builtin_amdgcn_s_setprio(1);
        #pragma unroll
        for (int kb = 0; kb < 2; kb++) {
            bf16x8 ap = *(const bf16x8*)(PsC + l15 * 144 + kb * 64 + g16);
            #pragma unroll
            for (int c2 = 0; c2 < 4; c2++) {
                int vrow = c2 * 16 + l15;
                int voff = vrow * 128 + (((kb << 6) | g16) ^ ((vrow & 7) << 4));
                bf16x8 bv = *(const bf16x8*)(VsC + cur * 8192 + voff);
                acc_o[c2] = __builtin_amdgcn_mfma_f32_16x16x32_bf16(ap, bv, acc_o[c2], 0, 0, 0);
            }
        }
        __builtin_amdgcn_s_setprio(0);

        if (kt < 15) __syncthreads();   // next tile staged + all reads done
    }
#undef STAGE_KV

    // finalize l: reduce 4 lanes sharing q=l15, redistribute to O-fragment rows
    lp += __shfl_xor(lp, 16, 64);
    lp += __shfl_xor(lp, 32, 64);
    float linv[4];
    #pragma unroll
    for (int reg = 0; reg < 4; reg++)
        linv[reg] = 1.0f / __shfl(lp, ((lane >> 4) << 2) + reg, 64);

    // epilogue: AO [8192][1024] hi only
    #pragma unroll
    for (int c2 = 0; c2 < 4; c2++) {
        int col = h * 64 + c2 * 16 + l15;
        #pragma unroll
        for (int reg = 0; reg < 4; reg++) {
            int row = b * 1024 + qt * 64 + w * 16 + (lane >> 4) * 4 + reg;
            float v = acc_o[c2][reg] * linv[reg];
            AO[(size_t)row * 1024 + col] = f2bf(v);
        }
    }
}

// ---------------------------------------------------------------------------
extern "C" void kernel_launch(void* const* d_in, const int* in_sizes, int n_in,
                              void* d_out, int out_size, void* d_ws, size_t ws_size,
                              hipStream_t stream) {
    const float* x    = (const float*)d_in[0];   // [8,1024,1024]
    const float* Wqkv = (const float*)d_in[1];   // [1024,3072]
    const float* Wout = (const float*)d_in[2];   // [1024,1024]
    float* out = (float*)d_out;                  // [8,1024,1024] f32

    u16* xt    = (u16*)d_ws;                     // [8192][1024] hi
    u16* wqk   = xt + 8192ull * 1024;            // [2048][1024] hi
    u16* wv    = wqk + 2048ull * 1024;           // [1024][1024] hi
    u16* woutt = wv + 1024ull * 1024;            // [1024][1024] hi
    u16* Qh    = woutt + 1024ull * 1024;         // [128][1024][64] (x log2e/8)
    u16* Kh    = Qh + 128ull * 1024 * 64;        // [128][1024][64]
    u16* Vtr   = Kh + 128ull * 1024 * 64;        // [128][64][1024]
    u16* AO    = xt;                             // [8192][1024] hi (alias)

    convert_x<<<4096, 256, 0, stream>>>(x, xt);
    conv_w<<<dim3(96, 32), 256, 0, stream>>>(Wqkv, wqk, wv);
    conv_wout<<<dim3(32, 32), 256, 0, stream>>>(Wout, woutt);

    // Q,K projection: x_hi . W_hi, K'=1024, grid 256 blocks (exactly 1 round)
    gemm_qk_8ph<<<256, 512, 0, stream>>>(xt, wqk, Qh, Kh, 1024, 8);

    // V projection: hi-only K=1024
    gemm_bf16<2><<<512, 256, 0, stream>>>(
        xt, 1024, wv, 1024, 1024, nullptr, Vtr, 1024, 8);

    attn_mfma<<<2048, 256, 0, stream>>>(Qh, Kh, Vtr, AO);

    // output projection: AO_hi . W_hi, K=1024
    gemm_bf16<0><<<512, 256, 0, stream>>>(
        AO, 1024, woutt, 1024, 1024, out, nullptr, 1024, 8);
}

// Round 17
// 159.452 us; speedup vs baseline: 1.0222x; 1.0222x over previous
//
#include <hip/hip_runtime.h>
#include <math.h>

#define NH 16
#define HD 64

typedef unsigned short u16;
typedef unsigned int   u32;
using bf16x8 = __attribute__((ext_vector_type(8))) short;
using f32x4  = __attribute__((ext_vector_type(4))) float;
using u16x8  = __attribute__((ext_vector_type(8))) unsigned short;
using u16x4  = __attribute__((ext_vector_type(4))) unsigned short;
using u32x2  = __attribute__((ext_vector_type(2))) unsigned int;

__device__ __forceinline__ u16 f2bf(float x) {
    u32 u = __float_as_uint(x);
    u32 r = (u + 0x7FFFu + ((u >> 16) & 1u)) >> 16;
    return (u16)r;
}
__device__ __forceinline__ float bf2f(u16 h) { return __uint_as_float(((u32)h) << 16); }

#define GLDS16(src, dst) __builtin_amdgcn_global_load_lds( \
    (const __attribute__((address_space(1))) void*)(src),  \
    (__attribute__((address_space(3))) void*)(dst), 16, 0, 0)

#define LDS_OFF(p) ((u32)(uintptr_t)(__attribute__((address_space(3))) void*)(p))
#define DSREAD(d, a) asm volatile("ds_read_b128 %0, %1" : "=v"(d) : "v"(a))

#define MEMFENCE asm volatile("" ::: "memory")
#define BARMID { MEMFENCE; __builtin_amdgcn_s_barrier(); \
                 asm volatile("s_waitcnt lgkmcnt(0)" ::: "memory"); \
                 __builtin_amdgcn_sched_barrier(0); }
#define BAREND { MEMFENCE; __builtin_amdgcn_s_barrier(); MEMFENCE; }
#define VMW(n) asm volatile("s_waitcnt vmcnt(" #n ")" ::: "memory")

// ---------------------------------------------------------------------------
// x [8192][1024] f32 -> xt [8192][1024] bf16 (hi only)
__global__ __launch_bounds__(256) void convert_x(const float* __restrict__ x,
                                                 u16* __restrict__ xt) {
    int t = blockIdx.x * 256 + threadIdx.x;
    int m = t >> 7;
    int k = (t & 127) * 8;
    const float4* src = (const float4*)(x + (size_t)m * 1024 + k);
    float4 v0 = src[0], v1 = src[1];
    float vs[8] = {v0.x, v0.y, v0.z, v0.w, v1.x, v1.y, v1.z, v1.w};
    u16x8 hv;
    #pragma unroll
    for (int j = 0; j < 8; j++) hv[j] = f2bf(vs[j]);
    *(u16x8*)(xt + (size_t)m * 1024 + k) = hv;
}

// ---------------------------------------------------------------------------
// Wqkv [1024][3072] f32 -> transposed hi:
//   cols 0..2047   (Q,K): wqk [2048][1024]
//   cols 2048..3071 (V) : wv  [1024][1024]
__global__ __launch_bounds__(256) void conv_w(const float* __restrict__ W,
                                              u16* __restrict__ wqk,
                                              u16* __restrict__ wv) {
    __shared__ float Ts[32][33];
    const int N = 3072;
    int k0 = blockIdx.y * 32, n0 = blockIdx.x * 32;
    int t = threadIdx.x;
    int r = t >> 3, c4 = (t & 7) * 4;
    float4 v = *(const float4*)(W + (size_t)(k0 + r) * N + n0 + c4);
    Ts[r][c4] = v.x; Ts[r][c4 + 1] = v.y; Ts[r][c4 + 2] = v.z; Ts[r][c4 + 3] = v.w;
    __syncthreads();
    int nl = t >> 3, kl = (t & 7) * 4;
    u16x4 hv;
    #pragma unroll
    for (int j = 0; j < 4; j++) hv[j] = f2bf(Ts[kl + j][nl]);
    int col = n0 + nl;
    if (col < 2048) {
        *(u16x4*)&wqk[(size_t)col * 1024 + k0 + kl] = hv;
    } else {
        *(u16x4*)&wv[(size_t)(col - 2048) * 1024 + k0 + kl] = hv;
    }
}

// ---------------------------------------------------------------------------
// Wout [1024][1024] f32 -> Wt [1024][1024] bf16 hi (transposed)
__global__ __launch_bounds__(256) void conv_wout(const float* __restrict__ W,
                                                 u16* __restrict__ Wt) {
    __shared__ float Ts[32][33];
    const int N = 1024;
    int k0 = blockIdx.y * 32, n0 = blockIdx.x * 32;
    int t = threadIdx.x;
    int r = t >> 3, c4 = (t & 7) * 4;
    float4 v = *(const float4*)(W + (size_t)(k0 + r) * N + n0 + c4);
    Ts[r][c4] = v.x; Ts[r][c4 + 1] = v.y; Ts[r][c4 + 2] = v.z; Ts[r][c4 + 3] = v.w;
    __syncthreads();
    int nl = t >> 3, kl = (t & 7) * 4;
    u16x4 hv;
    #pragma unroll
    for (int j = 0; j < 4; j++) hv[j] = f2bf(Ts[kl + j][nl]);
    *(u16x4*)&Wt[(size_t)(n0 + nl) * 1024 + k0 + kl] = hv;
}

// ---------------------------------------------------------------------------
// 256x256 8-phase GEMM: Q,K projection (N=2048 -> grid exactly 256, Kp=1024).
// Epilogue: Q pre-scaled by (1/8)*log2(e) for exp2-based softmax; K plain.
__global__ __launch_bounds__(512, 2)
void gemm_qk_8ph(const u16* __restrict__ A, const u16* __restrict__ Bt,
                 u16* __restrict__ Qh, u16* __restrict__ Kh,
                 int Kp, int nbx) {
    __shared__ char LDS[131072];
    char* ldsA = LDS;
    char* ldsB = LDS + 65536;
    const u32 ldsAoff = LDS_OFF(ldsA);
    const u32 ldsBoff = ldsAoff + 65536;

    const int tid = threadIdx.x, lane = tid & 63, w = tid >> 6;
    const int wr = w >> 2, wc = w & 3;
    const int l15 = lane & 15;
    const int khb = (lane >> 4) << 4;
    const int lswz = (l15 & 7) << 4;
    const int Kp2 = Kp * 2;

    const int cpx = (int)gridDim.x >> 3;
    const int wg  = ((int)blockIdx.x & 7) * cpx + ((int)blockIdx.x >> 3);
    const int m0 = (wg / nbx) * 256, n0 = (wg % nbx) * 256;

    const int tp = tid >> 3;
    const int sw = ((tid & 7) * 16) ^ ((tp & 7) << 4);
    const int nA = ((tp >> 5) << 6) + (tp & 31);

    const char* Agb = (const char*)A  + (size_t)m0 * Kp2;
    const char* Bgb = (const char*)Bt + (size_t)n0 * Kp2;

#define STAGE_A(t, h, buf) { \
    const char* s_ = Agb + (t) * 128 + ((h) * 64 + tp) * Kp2 + sw; \
    char* d_ = ldsA + (buf) * 32768 + (h) * 16384 + (w << 10); \
    GLDS16(s_, d_); GLDS16(s_ + (size_t)128 * Kp2, d_ + 8192); }
#define STAGE_B(t, h, buf) { \
    const char* s_ = Bgb + (t) * 128 + (nA + (h) * 32) * Kp2 + sw; \
    char* d_ = ldsB + (buf) * 32768 + (h) * 16384 + (w << 10); \
    GLDS16(s_, d_); GLDS16(s_ + (size_t)128 * Kp2, d_ + 8192); }

    bf16x8 Af[4][2], Bf[2][2];

#define LOADA(buf, mh) { \
    _Pragma("unroll") \
    for (int mi = 0; mi < 4; ++mi) { \
        u32 rb_ = ldsAoff + (buf) * 32768 + (mh) * 16384 \
                + (u32)((wr * 64 + mi * 16 + l15) * 128); \
        DSREAD(Af[mi][0], rb_ + (u32)((khb) ^ lswz)); \
        DSREAD(Af[mi][1], rb_ + (u32)((64 + khb) ^ lswz)); \
    } }
#define LOADB(buf, nh) { \
    _Pragma("unroll") \
    for (int ni = 0; ni < 2; ++ni) { \
        u32 rb_ = ldsBoff + (buf) * 32768 + (nh) * 16384 \
                + (u32)((wc * 32 + ni * 16 + l15) * 128); \
        DSREAD(Bf[ni][0], rb_ + (u32)((khb) ^ lswz)); \
        DSREAD(Bf[ni][1], rb_ + (u32)((64 + khb) ^ lswz)); \
    } }
#define MM(mh, nh) { \
    __builtin_amdgcn_s_setprio(1); \
    _Pragma("unroll") \
    for (int kk = 0; kk < 2; ++kk) \
        _Pragma("unroll") \
        for (int mi = 0; mi < 4; ++mi) \
            _Pragma("unroll") \
            for (int ni = 0; ni < 2; ++ni) \
                acc[(mh) * 4 + mi][(nh) * 2 + ni] = \
                    __builtin_amdgcn_mfma_f32_16x16x32_bf16( \
                        Af[mi][kk], Bf[ni][kk], acc[(mh) * 4 + mi][(nh) * 2 + ni], 0, 0, 0); \
    __builtin_amdgcn_s_setprio(0); }

    f32x4 acc[8][4];
    #pragma unroll
    for (int i = 0; i < 8; i++)
        #pragma unroll
        for (int j = 0; j < 4; j++)
            acc[i][j] = f32x4{0.f, 0.f, 0.f, 0.f};

    const int NT = Kp >> 6;
    const int NITER = NT / 2 - 1;

    STAGE_B(0, 0, 0); STAGE_A(0, 1, 0); STAGE_B(0, 1, 0); STAGE_A(0, 0, 0);
    STAGE_B(1, 0, 1); STAGE_A(1, 1, 1); STAGE_B(1, 1, 1);
    VMW(6);
    MEMFENCE; __builtin_amdgcn_s_barrier(); MEMFENCE;

    for (int it = 0; it < NITER; ++it) {
        const int t = 2 * it;
        LOADA(0, 0); LOADB(0, 0); STAGE_A(t + 1, 0, 1);
        BARMID; MM(0, 0); BAREND;
        LOADA(0, 1); STAGE_B(t + 2, 0, 0);
        BARMID; MM(1, 0); BAREND;
        LOADB(0, 1); STAGE_A(t + 2, 1, 0);
        BARMID; MM(1, 1); BAREND;
        LOADA(0, 0); STAGE_B(t + 2, 1, 0); VMW(6);
        BARMID; MM(0, 1); BAREND;
        LOADA(1, 0); LOADB(1, 0); STAGE_A(t + 2, 0, 0);
        BARMID; MM(0, 0); BAREND;
        LOADA(1, 1); STAGE_B(t + 3, 0, 1);
        BARMID; MM(1, 0); BAREND;
        LOADB(1, 1); STAGE_A(t + 3, 1, 1);
        BARMID; MM(1, 1); BAREND;
        LOADA(1, 0); STAGE_B(t + 3, 1, 1); VMW(6);
        BARMID; MM(0, 1); BAREND;
    }

    LOADA(0, 0); LOADB(0, 0); STAGE_A(NT - 1, 0, 1);
    BARMID; MM(0, 0); BAREND;
    LOADA(0, 1);
    BARMID; MM(1, 0); BAREND;
    LOADB(0, 1);
    BARMID; MM(1, 1); BAREND;
    LOADA(0, 0); VMW(0);
    BARMID; MM(0, 1); BAREND;
    LOADA(1, 0); LOADB(1, 0);
    BARMID; MM(0, 0); BAREND;
    LOADA(1, 1);
    BARMID; MM(1, 0); BAREND;
    LOADB(1, 1);
    BARMID; MM(1, 1); BAREND;
    LOADA(1, 0);
    BARMID; MM(0, 1); BAREND;

    const int sel = n0 >> 10;   // 0 = Q, 1 = K
    u16* dst = (sel == 0) ? Qh : Kh;
    // Q scale folds 1/sqrt(64) and log2(e) (softmax uses exp2)
    const float sc = (sel == 0) ? 0.125f * 1.4426950408889634f : 1.0f;
    #pragma unroll
    for (int mh = 0; mh < 2; ++mh)
        #pragma unroll
        for (int mi = 0; mi < 4; ++mi)
            #pragma unroll
            for (int nh = 0; nh < 2; ++nh)
                #pragma unroll
                for (int ni = 0; ni < 2; ++ni) {
                    f32x4 a = acc[mh * 4 + mi][nh * 2 + ni];
                    int col = n0 + wc * 64 + nh * 32 + ni * 16 + l15;
                    int within = col & 1023;
                    int hh = within >> 6, d = within & 63;
                    int rowb = m0 + wr * 128 + mh * 64 + mi * 16 + (lane >> 4) * 4;
                    int bb = rowb >> 10, n = rowb & 1023;
                    size_t hn = (size_t)(bb * NH + hh) * 1024 + n;
                    #pragma unroll
                    for (int reg = 0; reg < 4; reg++)
                        dst[(hn + reg) * 64 + d] = f2bf(a[reg] * sc);
                }
#undef STAGE_A
#undef STAGE_B
#undef LOADA
#undef LOADB
#undef MM
}

// ---------------------------------------------------------------------------
// 128x128 bf16 GEMM, m97 structure, strided A/B (lda/ldb in elements).
// MODE 0: C f32 [M][N].  MODE 2: V write transposed -> Vtr [head][64][1024].
template<int MODE>
__global__ __launch_bounds__(256, 2)
void gemm_bf16(const u16* __restrict__ A, int lda,
               const u16* __restrict__ Bt, int ldb, int Kloop,
               float* __restrict__ C, u16* __restrict__ Vtr, int N, int nbx) {
    __shared__ u16 As[128 * 64];
    __shared__ u16 Bs[128 * 64];
    const char* AsC = (const char*)As;
    const char* BsC = (const char*)Bs;

    const int t = threadIdx.x;
    const int lane = t & 63, w = t >> 6;

    const int cpx = (int)gridDim.x >> 3;
    const int wg  = (blockIdx.x & 7) * cpx + (blockIdx.x >> 3);
    const int m0 = (wg / nbx) * 128, n0 = (wg % nbx) * 128;

    const int l15 = lane & 15;
    const int g16 = (lane >> 4) << 4;
    const int swz = (l15 & 7) << 4;

    const char* srcA[4];
    const char* srcB[4];
    char* dstA[4];
    char* dstB[4];
    #pragma unroll
    for (int i = 0; i < 4; i++) {
        int s = (w * 4 + i) * 64 + lane;
        int row  = (s * 16) >> 7;
        int colb = (s * 16) & 127;
        int scol = colb ^ ((row & 7) << 4);
        srcA[i] = (const char*)A  + ((size_t)(m0 + row) * lda) * 2 + scol;
        srcB[i] = (const char*)Bt + ((size_t)(n0 + row) * ldb) * 2 + scol;
        dstA[i] = (char*)As + (w * 4 + i) * 1024;
        dstB[i] = (char*)Bs + (w * 4 + i) * 1024;
    }

    const int wm = (w >> 1) * 64, wn = (w & 1) * 64;
    int rA[4], rB[4];
    #pragma unroll
    for (int i = 0; i < 4; i++) {
        rA[i] = (wm + i * 16 + l15) * 128;
        rB[i] = (wn + i * 16 + l15) * 128;
    }

    f32x4 acc[4][4];
    #pragma unroll
    for (int i = 0; i < 4; i++)
        #pragma unroll
        for (int j = 0; j < 4; j++)
            acc[i][j] = f32x4{0.f, 0.f, 0.f, 0.f};

    for (int k0 = 0; k0 < Kloop; k0 += 64) {
        __syncthreads();
        #pragma unroll
        for (int i = 0; i < 4; i++) {
            GLDS16(srcA[i], dstA[i]);
            GLDS16(srcB[i], dstB[i]);
            srcA[i] += 128;
            srcB[i] += 128;
        }
        __syncthreads();
        #pragma unroll
        for (int kb = 0; kb < 2; kb++) {
            const int csw = ((kb << 6) | g16) ^ swz;
            bf16x8 af[4], bfr[4];
            #pragma unroll
            for (int mi = 0; mi < 4; mi++) af[mi]  = *(const bf16x8*)(AsC + rA[mi] + csw);
            #pragma unroll
            for (int ni = 0; ni < 4; ni++) bfr[ni] = *(const bf16x8*)(BsC + rB[ni] + csw);
            #pragma unroll
            for (int mi = 0; mi < 4; mi++)
                #pragma unroll
                for (int ni = 0; ni < 4; ni++)
                    acc[mi][ni] = __builtin_amdgcn_mfma_f32_16x16x32_bf16(
                        af[mi], bfr[ni], acc[mi][ni], 0, 0, 0);
        }
    }

    if (MODE == 0) {
        #pragma unroll
        for (int mi = 0; mi < 4; mi++) {
            int rowb = m0 + wm + mi * 16 + (lane >> 4) * 4;
            #pragma unroll
            for (int ni = 0; ni < 4; ni++) {
                int col = n0 + wn + ni * 16 + l15;
                #pragma unroll
                for (int reg = 0; reg < 4; reg++)
                    C[(size_t)(rowb + reg) * N + col] = acc[mi][ni][reg];
            }
        }
    } else {
        // V: write transposed [head][d][key]
        #pragma unroll
        for (int ni = 0; ni < 4; ni++) {
            int col = n0 + wn + ni * 16 + l15;      // 0..1023
            int hh = col >> 6, d = col & 63;
            #pragma unroll
            for (int mi = 0; mi < 4; mi++) {
                int rowb = m0 + wm + mi * 16 + (lane >> 4) * 4;
                int bb = rowb >> 10, n = rowb & 1023;
                u16x4 vv;
                #pragma unroll
                for (int reg = 0; reg < 4; reg++)
                    vv[reg] = f2bf(acc[mi][ni][reg]);
                *(u16x4*)&Vtr[((size_t)(bb * NH + hh) * 64 + d) * 1024 + n] = vv;
            }
        }
    }
}

// ---------------------------------------------------------------------------
// Flash attention, swapped-QK^T (T12), R15-proven structure (T14 reg-staged
// K/V, 2 barriers/kt, 144B-stride P rows). Q pre-scaled by 0.125*log2e ->
// softmax via exp2 (raw v_exp_f32, no per-element mul). AO hi [8192][1024].
__global__ __launch_bounds__(256, 4)
void attn_mfma(const u16* __restrict__ Qh, const u16* __restrict__ Kh,
               const u16* __restrict__ Vt, u16* __restrict__ AO) {
    __shared__ u16 Ks[64 * 64];
    __shared__ u16 Vs[64 * 64];
    __shared__ u16 Ps[4][16 * 72];

    const int t = threadIdx.x, lane = t & 63, w = t >> 6;

    const int orig = blockIdx.x;
    const int xcd = orig & 7, slot = orig >> 3;
    const int head_lin = xcd * 16 + (slot >> 4);
    const int qt = slot & 15;
    const int b = head_lin >> 4, h = head_lin & 15;
    const size_t head = (size_t)head_lin;

    const char* Qg = (const char*)(Qh + head * 1024 * 64) + qt * 64 * 128;
    const char* Kg = (const char*)(Kh + head * 1024 * 64);
    const char* Vg = (const char*)(Vt + head * 64 * 1024);
    char* KsC = (char*)Ks;
    char* VsC = (char*)Vs;
    char* PsC = (char*)(&Ps[w][0]);

    const int l15 = lane & 15;
    const int g16 = (lane >> 4) << 4;
    const int g8  = (lane >> 4) << 3;

    // stage K/V tile 0 (gload_lds, pre-swizzled source, linear LDS dest)
    #pragma unroll
    for (int i = 0; i < 2; i++) {
        int c = (w * 2 + i) * 64 + lane;
        int row = c >> 3, colb = (c & 7) * 16;
        int soff = colb ^ ((row & 7) << 4);
        GLDS16(Kg + row * 128 + soff, KsC + (w * 2 + i) * 1024);
        GLDS16(Vg + row * 2048 + soff, VsC + (w * 2 + i) * 1024);
    }

    // Q fragments from global (row-major [64 q][64 d], 128B rows)
    const int qrow = w * 16 + l15;
    bf16x8 qf[2];
    #pragma unroll
    for (int kk = 0; kk < 2; kk++)
        qf[kk] = *(const bf16x8*)(Qg + qrow * 128 + kk * 64 + g16);

    int ksrcoff[2], kdst[2], vsrcoff[2], vdst[2];
    #pragma unroll
    for (int i = 0; i < 2; i++) {
        int c = i * 256 + t;
        int row = c >> 3, colb = (c & 7) * 16;
        ksrcoff[i] = c * 16;
        kdst[i]    = row * 128 + (colb ^ ((row & 7) << 4));
        vsrcoff[i] = row * 2048 + colb;
        vdst[i]    = row * 128 + (colb ^ ((row & 7) << 4));
    }

    float lp = 0.f;                     // partial softmax denom for q = l15
    f32x4 acc_o[4];
    #pragma unroll
    for (int i = 0; i < 4; i++) acc_o[i] = f32x4{0.f, 0.f, 0.f, 0.f};

    __syncthreads();

    for (int kt = 0; kt < 16; kt++) {
        // T14 issue-early: next tile's K/V -> regs
        u16x8 kst[2], vst[2];
        if (kt < 15) {
            const char* ks = Kg + (kt + 1) * 8192;
            const char* vs = Vg + (kt + 1) * 128;
            #pragma unroll
            for (int i = 0; i < 2; i++) {
                kst[i] = *(const u16x8*)(ks + ksrcoff[i]);
                vst[i] = *(const u16x8*)(vs + vsrcoff[i]);
            }
        }

        // S^T = K Q^T (swapped operands): lane holds S^T[k=c*16+4g+reg][q=l15]
        f32x4 sacc[4];
        #pragma unroll
        for (int c = 0; c < 4; c++) sacc[c] = f32x4{0.f, 0.f, 0.f, 0.f};
        __builtin_amdgcn_s_setprio(1);
        #pragma unroll
        for (int kk = 0; kk < 2; kk++) {
            int csw = ((kk * 64) | g16) ^ ((l15 & 7) << 4);
            #pragma unroll
            for (int c = 0; c < 4; c++) {
                bf16x8 bk = *(const bf16x8*)(KsC + (c * 16 + l15) * 128 + csw);
                sacc[c] = __builtin_amdgcn_mfma_f32_16x16x32_bf16(bk, qf[kk], sacc[c], 0, 0, 0);
            }
        }
        __builtin_amdgcn_s_setprio(0);

        // P = exp2(S) (Q pre-scaled by log2e); lane-partial l; cvt_pk pack ->
        // one short-typed b64 store per block (144B-stride rows)
        {
            char* pb = PsC + l15 * 144 + g8;
            #pragma unroll
            for (int c = 0; c < 4; c++) {
                float p0 = exp2f(sacc[c][0]);
                float p1 = exp2f(sacc[c][1]);
                float p2 = exp2f(sacc[c][2]);
                float p3 = exp2f(sacc[c][3]);
                lp += (p0 + p1) + (p2 + p3);
                u32 w0, w1;
                asm("v_cvt_pk_bf16_f32 %0, %1, %2" : "=v"(w0) : "v"(p0), "v"(p1));
                asm("v_cvt_pk_bf16_f32 %0, %1, %2" : "=v"(w1) : "v"(p2), "v"(p3));
                u16x4 pk = __builtin_bit_cast(u16x4, u32x2{w0, w1});
                *(u16x4*)(pb + c * 32) = pk;
            }
        }
        // pin ordering: P writes complete before PV reads (compiler + HW)
        MEMFENCE;
        asm volatile("s_waitcnt lgkmcnt(0)" ::: "memory");
        __builtin_amdgcn_sched_barrier(0);

        // O += P @ V  (P read: row l15 at 144B stride)
        __builtin_amdgcn_s_setprio(1);
        #pragma unroll
        for (int kb = 0; kb < 2; kb++) {
            bf16x8 ap = *(const bf16x8*)(PsC + l15 * 144 + kb * 64 + g16);
            #pragma unroll
            for (int c2 = 0; c2 < 4; c2++) {
                int vrow = c2 * 16 + l15;
                int voff = vrow * 128 + (((kb << 6) | g16) ^ ((vrow & 7) << 4));
                bf16x8 bv = *(const bf16x8*)(VsC + voff);
                acc_o[c2] = __builtin_amdgcn_mfma_f32_16x16x32_bf16(ap, bv, acc_o[c2], 0, 0, 0);
            }
        }
        __builtin_amdgcn_s_setprio(0);

        __syncthreads();
        if (kt < 15) {
            #pragma unroll
            for (int i = 0; i < 2; i++) {
                *(u16x8*)(KsC + kdst[i]) = kst[i];
                *(u16x8*)(VsC + vdst[i]) = vst[i];
            }
            __syncthreads();
        }
    }

    // finalize l: reduce 4 lanes sharing q=l15, redistribute to O-fragment rows
    lp += __shfl_xor(lp, 16, 64);
    lp += __shfl_xor(lp, 32, 64);
    float linv[4];
    #pragma unroll
    for (int reg = 0; reg < 4; reg++)
        linv[reg] = 1.0f / __shfl(lp, ((lane >> 4) << 2) + reg, 64);

    // epilogue: AO [8192][1024] hi only
    #pragma unroll
    for (int c2 = 0; c2 < 4; c2++) {
        int col = h * 64 + c2 * 16 + l15;
        #pragma unroll
        for (int reg = 0; reg < 4; reg++) {
            int row = b * 1024 + qt * 64 + w * 16 + (lane >> 4) * 4 + reg;
            float v = acc_o[c2][reg] * linv[reg];
            AO[(size_t)row * 1024 + col] = f2bf(v);
        }
    }
}

// ---------------------------------------------------------------------------
extern "C" void kernel_launch(void* const* d_in, const int* in_sizes, int n_in,
                              void* d_out, int out_size, void* d_ws, size_t ws_size,
                              hipStream_t stream) {
    const float* x    = (const float*)d_in[0];   // [8,1024,1024]
    const float* Wqkv = (const float*)d_in[1];   // [1024,3072]
    const float* Wout = (const float*)d_in[2];   // [1024,1024]
    float* out = (float*)d_out;                  // [8,1024,1024] f32

    u16* xt    = (u16*)d_ws;                     // [8192][1024] hi
    u16* wqk   = xt + 8192ull * 1024;            // [2048][1024] hi
    u16* wv    = wqk + 2048ull * 1024;           // [1024][1024] hi
    u16* woutt = wv + 1024ull * 1024;            // [1024][1024] hi
    u16* Qh    = woutt + 1024ull * 1024;         // [128][1024][64] (x log2e/8)
    u16* Kh    = Qh + 128ull * 1024 * 64;        // [128][1024][64]
    u16* Vtr   = Kh + 128ull * 1024 * 64;        // [128][64][1024]
    u16* AO    = xt;                             // [8192][1024] hi (alias)

    convert_x<<<4096, 256, 0, stream>>>(x, xt);
    conv_w<<<dim3(96, 32), 256, 0, stream>>>(Wqkv, wqk, wv);
    conv_wout<<<dim3(32, 32), 256, 0, stream>>>(Wout, woutt);

    // Q,K projection: x_hi . W_hi, K'=1024, grid 256 blocks (exactly 1 round)
    gemm_qk_8ph<<<256, 512, 0, stream>>>(xt, wqk, Qh, Kh, 1024, 8);

    // V projection: hi-only K=1024
    gemm_bf16<2><<<512, 256, 0, stream>>>(
        xt, 1024, wv, 1024, 1024, nullptr, Vtr, 1024, 8);

    attn_mfma<<<2048, 256, 0, stream>>>(Qh, Kh, Vtr, AO);

    // output projection: AO_hi . W_hi, K=1024
    gemm_bf16<0><<<512, 256, 0, stream>>>(
        AO, 1024, woutt, 1024, 1024, out, nullptr, 1024, 8);
}

// Round 18
// 152.963 us; speedup vs baseline: 1.0656x; 1.0424x over previous
//
#include <hip/hip_runtime.h>
#include <math.h>

#define NH 16
#define HD 64

typedef unsigned short u16;
typedef unsigned int   u32;
using bf16x8 = __attribute__((ext_vector_type(8))) short;
using f32x4  = __attribute__((ext_vector_type(4))) float;
using u16x8  = __attribute__((ext_vector_type(8))) unsigned short;
using u16x4  = __attribute__((ext_vector_type(4))) unsigned short;
using u32x2  = __attribute__((ext_vector_type(2))) unsigned int;

__device__ __forceinline__ u16 f2bf(float x) {
    u32 u = __float_as_uint(x);
    u32 r = (u + 0x7FFFu + ((u >> 16) & 1u)) >> 16;
    return (u16)r;
}
__device__ __forceinline__ float bf2f(u16 h) { return __uint_as_float(((u32)h) << 16); }

#define GLDS16(src, dst) __builtin_amdgcn_global_load_lds( \
    (const __attribute__((address_space(1))) void*)(src),  \
    (__attribute__((address_space(3))) void*)(dst), 16, 0, 0)

#define LDS_OFF(p) ((u32)(uintptr_t)(__attribute__((address_space(3))) void*)(p))
#define DSREAD(d, a) asm volatile("ds_read_b128 %0, %1" : "=v"(d) : "v"(a))

#define MEMFENCE asm volatile("" ::: "memory")
#define BARMID { MEMFENCE; __builtin_amdgcn_s_barrier(); \
                 asm volatile("s_waitcnt lgkmcnt(0)" ::: "memory"); \
                 __builtin_amdgcn_sched_barrier(0); }
#define BAREND { MEMFENCE; __builtin_amdgcn_s_barrier(); MEMFENCE; }
#define VMW(n) asm volatile("s_waitcnt vmcnt(" #n ")" ::: "memory")

// ---------------------------------------------------------------------------
// x [8192][1024] f32 -> xt [8192][1024] bf16 (hi only)
__global__ __launch_bounds__(256) void convert_x(const float* __restrict__ x,
                                                 u16* __restrict__ xt) {
    int t = blockIdx.x * 256 + threadIdx.x;
    int m = t >> 7;
    int k = (t & 127) * 8;
    const float4* src = (const float4*)(x + (size_t)m * 1024 + k);
    float4 v0 = src[0], v1 = src[1];
    float vs[8] = {v0.x, v0.y, v0.z, v0.w, v1.x, v1.y, v1.z, v1.w};
    u16x8 hv;
    #pragma unroll
    for (int j = 0; j < 8; j++) hv[j] = f2bf(vs[j]);
    *(u16x8*)(xt + (size_t)m * 1024 + k) = hv;
}

// ---------------------------------------------------------------------------
// Wqkv [1024][3072] f32 -> transposed hi:
//   cols 0..2047   (Q,K): wqk [2048][1024]
//   cols 2048..3071 (V) : wv  [1024][1024]
__global__ __launch_bounds__(256) void conv_w(const float* __restrict__ W,
                                              u16* __restrict__ wqk,
                                              u16* __restrict__ wv) {
    __shared__ float Ts[32][33];
    const int N = 3072;
    int k0 = blockIdx.y * 32, n0 = blockIdx.x * 32;
    int t = threadIdx.x;
    int r = t >> 3, c4 = (t & 7) * 4;
    float4 v = *(const float4*)(W + (size_t)(k0 + r) * N + n0 + c4);
    Ts[r][c4] = v.x; Ts[r][c4 + 1] = v.y; Ts[r][c4 + 2] = v.z; Ts[r][c4 + 3] = v.w;
    __syncthreads();
    int nl = t >> 3, kl = (t & 7) * 4;
    u16x4 hv;
    #pragma unroll
    for (int j = 0; j < 4; j++) hv[j] = f2bf(Ts[kl + j][nl]);
    int col = n0 + nl;
    if (col < 2048) {
        *(u16x4*)&wqk[(size_t)col * 1024 + k0 + kl] = hv;
    } else {
        *(u16x4*)&wv[(size_t)(col - 2048) * 1024 + k0 + kl] = hv;
    }
}

// ---------------------------------------------------------------------------
// Wout [1024][1024] f32 -> Wt [1024][1024] bf16 hi (transposed)
__global__ __launch_bounds__(256) void conv_wout(const float* __restrict__ W,
                                                 u16* __restrict__ Wt) {
    __shared__ float Ts[32][33];
    const int N = 1024;
    int k0 = blockIdx.y * 32, n0 = blockIdx.x * 32;
    int t = threadIdx.x;
    int r = t >> 3, c4 = (t & 7) * 4;
    float4 v = *(const float4*)(W + (size_t)(k0 + r) * N + n0 + c4);
    Ts[r][c4] = v.x; Ts[r][c4 + 1] = v.y; Ts[r][c4 + 2] = v.z; Ts[r][c4 + 3] = v.w;
    __syncthreads();
    int nl = t >> 3, kl = (t & 7) * 4;
    u16x4 hv;
    #pragma unroll
    for (int j = 0; j < 4; j++) hv[j] = f2bf(Ts[kl + j][nl]);
    *(u16x4*)&Wt[(size_t)(n0 + nl) * 1024 + k0 + kl] = hv;
}

// ---------------------------------------------------------------------------
// 256x256 8-phase GEMM: Q,K projection (N=2048 -> grid exactly 256, Kp=1024).
// Epilogue: Q pre-scaled by (1/8)*log2(e) for exp2-based softmax; K plain.
__global__ __launch_bounds__(512, 2)
void gemm_qk_8ph(const u16* __restrict__ A, const u16* __restrict__ Bt,
                 u16* __restrict__ Qh, u16* __restrict__ Kh,
                 int Kp, int nbx) {
    __shared__ char LDS[131072];
    char* ldsA = LDS;
    char* ldsB = LDS + 65536;
    const u32 ldsAoff = LDS_OFF(ldsA);
    const u32 ldsBoff = ldsAoff + 65536;

    const int tid = threadIdx.x, lane = tid & 63, w = tid >> 6;
    const int wr = w >> 2, wc = w & 3;
    const int l15 = lane & 15;
    const int khb = (lane >> 4) << 4;
    const int lswz = (l15 & 7) << 4;
    const int Kp2 = Kp * 2;

    const int cpx = (int)gridDim.x >> 3;
    const int wg  = ((int)blockIdx.x & 7) * cpx + ((int)blockIdx.x >> 3);
    const int m0 = (wg / nbx) * 256, n0 = (wg % nbx) * 256;

    const int tp = tid >> 3;
    const int sw = ((tid & 7) * 16) ^ ((tp & 7) << 4);
    const int nA = ((tp >> 5) << 6) + (tp & 31);

    const char* Agb = (const char*)A  + (size_t)m0 * Kp2;
    const char* Bgb = (const char*)Bt + (size_t)n0 * Kp2;

#define STAGE_A(t, h, buf) { \
    const char* s_ = Agb + (t) * 128 + ((h) * 64 + tp) * Kp2 + sw; \
    char* d_ = ldsA + (buf) * 32768 + (h) * 16384 + (w << 10); \
    GLDS16(s_, d_); GLDS16(s_ + (size_t)128 * Kp2, d_ + 8192); }
#define STAGE_B(t, h, buf) { \
    const char* s_ = Bgb + (t) * 128 + (nA + (h) * 32) * Kp2 + sw; \
    char* d_ = ldsB + (buf) * 32768 + (h) * 16384 + (w << 10); \
    GLDS16(s_, d_); GLDS16(s_ + (size_t)128 * Kp2, d_ + 8192); }

    bf16x8 Af[4][2], Bf[2][2];

#define LOADA(buf, mh) { \
    _Pragma("unroll") \
    for (int mi = 0; mi < 4; ++mi) { \
        u32 rb_ = ldsAoff + (buf) * 32768 + (mh) * 16384 \
                + (u32)((wr * 64 + mi * 16 + l15) * 128); \
        DSREAD(Af[mi][0], rb_ + (u32)((khb) ^ lswz)); \
        DSREAD(Af[mi][1], rb_ + (u32)((64 + khb) ^ lswz)); \
    } }
#define LOADB(buf, nh) { \
    _Pragma("unroll") \
    for (int ni = 0; ni < 2; ++ni) { \
        u32 rb_ = ldsBoff + (buf) * 32768 + (nh) * 16384 \
                + (u32)((wc * 32 + ni * 16 + l15) * 128); \
        DSREAD(Bf[ni][0], rb_ + (u32)((khb) ^ lswz)); \
        DSREAD(Bf[ni][1], rb_ + (u32)((64 + khb) ^ lswz)); \
    } }
#define MM(mh, nh) { \
    __builtin_amdgcn_s_setprio(1); \
    _Pragma("unroll") \
    for (int kk = 0; kk < 2; ++kk) \
        _Pragma("unroll") \
        for (int mi = 0; mi < 4; ++mi) \
            _Pragma("unroll") \
            for (int ni = 0; ni < 2; ++ni) \
                acc[(mh) * 4 + mi][(nh) * 2 + ni] = \
                    __builtin_amdgcn_mfma_f32_16x16x32_bf16( \
                        Af[mi][kk], Bf[ni][kk], acc[(mh) * 4 + mi][(nh) * 2 + ni], 0, 0, 0); \
    __builtin_amdgcn_s_setprio(0); }

    f32x4 acc[8][4];
    #pragma unroll
    for (int i = 0; i < 8; i++)
        #pragma unroll
        for (int j = 0; j < 4; j++)
            acc[i][j] = f32x4{0.f, 0.f, 0.f, 0.f};

    const int NT = Kp >> 6;
    const int NITER = NT / 2 - 1;

    STAGE_B(0, 0, 0); STAGE_A(0, 1, 0); STAGE_B(0, 1, 0); STAGE_A(0, 0, 0);
    STAGE_B(1, 0, 1); STAGE_A(1, 1, 1); STAGE_B(1, 1, 1);
    VMW(6);
    MEMFENCE; __builtin_amdgcn_s_barrier(); MEMFENCE;

    for (int it = 0; it < NITER; ++it) {
        const int t = 2 * it;
        LOADA(0, 0); LOADB(0, 0); STAGE_A(t + 1, 0, 1);
        BARMID; MM(0, 0); BAREND;
        LOADA(0, 1); STAGE_B(t + 2, 0, 0);
        BARMID; MM(1, 0); BAREND;
        LOADB(0, 1); STAGE_A(t + 2, 1, 0);
        BARMID; MM(1, 1); BAREND;
        LOADA(0, 0); STAGE_B(t + 2, 1, 0); VMW(6);
        BARMID; MM(0, 1); BAREND;
        LOADA(1, 0); LOADB(1, 0); STAGE_A(t + 2, 0, 0);
        BARMID; MM(0, 0); BAREND;
        LOADA(1, 1); STAGE_B(t + 3, 0, 1);
        BARMID; MM(1, 0); BAREND;
        LOADB(1, 1); STAGE_A(t + 3, 1, 1);
        BARMID; MM(1, 1); BAREND;
        LOADA(1, 0); STAGE_B(t + 3, 1, 1); VMW(6);
        BARMID; MM(0, 1); BAREND;
    }

    LOADA(0, 0); LOADB(0, 0); STAGE_A(NT - 1, 0, 1);
    BARMID; MM(0, 0); BAREND;
    LOADA(0, 1);
    BARMID; MM(1, 0); BAREND;
    LOADB(0, 1);
    BARMID; MM(1, 1); BAREND;
    LOADA(0, 0); VMW(0);
    BARMID; MM(0, 1); BAREND;
    LOADA(1, 0); LOADB(1, 0);
    BARMID; MM(0, 0); BAREND;
    LOADA(1, 1);
    BARMID; MM(1, 0); BAREND;
    LOADB(1, 1);
    BARMID; MM(1, 1); BAREND;
    LOADA(1, 0);
    BARMID; MM(0, 1); BAREND;

    const int sel = n0 >> 10;   // 0 = Q, 1 = K
    u16* dst = (sel == 0) ? Qh : Kh;
    // Q scale folds 1/sqrt(64) and log2(e) (softmax uses exp2)
    const float sc = (sel == 0) ? 0.125f * 1.4426950408889634f : 1.0f;
    #pragma unroll
    for (int mh = 0; mh < 2; ++mh)
        #pragma unroll
        for (int mi = 0; mi < 4; ++mi)
            #pragma unroll
            for (int nh = 0; nh < 2; ++nh)
                #pragma unroll
                for (int ni = 0; ni < 2; ++ni) {
                    f32x4 a = acc[mh * 4 + mi][nh * 2 + ni];
                    int col = n0 + wc * 64 + nh * 32 + ni * 16 + l15;
                    int within = col & 1023;
                    int hh = within >> 6, d = within & 63;
                    int rowb = m0 + wr * 128 + mh * 64 + mi * 16 + (lane >> 4) * 4;
                    int bb = rowb >> 10, n = rowb & 1023;
                    size_t hn = (size_t)(bb * NH + hh) * 1024 + n;
                    #pragma unroll
                    for (int reg = 0; reg < 4; reg++)
                        dst[(hn + reg) * 64 + d] = f2bf(a[reg] * sc);
                }
#undef STAGE_A
#undef STAGE_B
#undef LOADA
#undef LOADB
#undef MM
}

// ---------------------------------------------------------------------------
// 128x128 bf16 GEMM, m97 structure, strided A/B (lda/ldb in elements).
// MODE 0: C f32 [M][N].  MODE 2: V write transposed -> Vtr [head][64][1024].
template<int MODE>
__global__ __launch_bounds__(256, 2)
void gemm_bf16(const u16* __restrict__ A, int lda,
               const u16* __restrict__ Bt, int ldb, int Kloop,
               float* __restrict__ C, u16* __restrict__ Vtr, int N, int nbx) {
    __shared__ u16 As[128 * 64];
    __shared__ u16 Bs[128 * 64];
    const char* AsC = (const char*)As;
    const char* BsC = (const char*)Bs;

    const int t = threadIdx.x;
    const int lane = t & 63, w = t >> 6;

    const int cpx = (int)gridDim.x >> 3;
    const int wg  = (blockIdx.x & 7) * cpx + (blockIdx.x >> 3);
    const int m0 = (wg / nbx) * 128, n0 = (wg % nbx) * 128;

    const int l15 = lane & 15;
    const int g16 = (lane >> 4) << 4;
    const int swz = (l15 & 7) << 4;

    const char* srcA[4];
    const char* srcB[4];
    char* dstA[4];
    char* dstB[4];
    #pragma unroll
    for (int i = 0; i < 4; i++) {
        int s = (w * 4 + i) * 64 + lane;
        int row  = (s * 16) >> 7;
        int colb = (s * 16) & 127;
        int scol = colb ^ ((row & 7) << 4);
        srcA[i] = (const char*)A  + ((size_t)(m0 + row) * lda) * 2 + scol;
        srcB[i] = (const char*)Bt + ((size_t)(n0 + row) * ldb) * 2 + scol;
        dstA[i] = (char*)As + (w * 4 + i) * 1024;
        dstB[i] = (char*)Bs + (w * 4 + i) * 1024;
    }

    const int wm = (w >> 1) * 64, wn = (w & 1) * 64;
    int rA[4], rB[4];
    #pragma unroll
    for (int i = 0; i < 4; i++) {
        rA[i] = (wm + i * 16 + l15) * 128;
        rB[i] = (wn + i * 16 + l15) * 128;
    }

    f32x4 acc[4][4];
    #pragma unroll
    for (int i = 0; i < 4; i++)
        #pragma unroll
        for (int j = 0; j < 4; j++)
            acc[i][j] = f32x4{0.f, 0.f, 0.f, 0.f};

    for (int k0 = 0; k0 < Kloop; k0 += 64) {
        __syncthreads();
        #pragma unroll
        for (int i = 0; i < 4; i++) {
            GLDS16(srcA[i], dstA[i]);
            GLDS16(srcB[i], dstB[i]);
            srcA[i] += 128;
            srcB[i] += 128;
        }
        __syncthreads();
        #pragma unroll
        for (int kb = 0; kb < 2; kb++) {
            const int csw = ((kb << 6) | g16) ^ swz;
            bf16x8 af[4], bfr[4];
            #pragma unroll
            for (int mi = 0; mi < 4; mi++) af[mi]  = *(const bf16x8*)(AsC + rA[mi] + csw);
            #pragma unroll
            for (int ni = 0; ni < 4; ni++) bfr[ni] = *(const bf16x8*)(BsC + rB[ni] + csw);
            #pragma unroll
            for (int mi = 0; mi < 4; mi++)
                #pragma unroll
                for (int ni = 0; ni < 4; ni++)
                    acc[mi][ni] = __builtin_amdgcn_mfma_f32_16x16x32_bf16(
                        af[mi], bfr[ni], acc[mi][ni], 0, 0, 0);
        }
    }

    if (MODE == 0) {
        #pragma unroll
        for (int mi = 0; mi < 4; mi++) {
            int rowb = m0 + wm + mi * 16 + (lane >> 4) * 4;
            #pragma unroll
            for (int ni = 0; ni < 4; ni++) {
                int col = n0 + wn + ni * 16 + l15;
                #pragma unroll
                for (int reg = 0; reg < 4; reg++)
                    C[(size_t)(rowb + reg) * N + col] = acc[mi][ni][reg];
            }
        }
    } else {
        // V: write transposed [head][d][key]
        #pragma unroll
        for (int ni = 0; ni < 4; ni++) {
            int col = n0 + wn + ni * 16 + l15;      // 0..1023
            int hh = col >> 6, d = col & 63;
            #pragma unroll
            for (int mi = 0; mi < 4; mi++) {
                int rowb = m0 + wm + mi * 16 + (lane >> 4) * 4;
                int bb = rowb >> 10, n = rowb & 1023;
                u16x4 vv;
                #pragma unroll
                for (int reg = 0; reg < 4; reg++)
                    vv[reg] = f2bf(acc[mi][ni][reg]);
                *(u16x4*)&Vtr[((size_t)(bb * NH + hh) * 64 + d) * 1024 + n] = vv;
            }
        }
    }
}

// ---------------------------------------------------------------------------
// Flash attention, swapped-QK^T (T12), R15-proven structure (T14 reg-staged
// K/V, 2 barriers/kt, 144B-stride P rows). Q pre-scaled by 0.125*log2e ->
// softmax via NATIVE exp2 (__builtin_amdgcn_exp2f = raw v_exp_f32; plain
// exp2f lowers to the precise OCML sequence and cost +18% VALU in R17).
__global__ __launch_bounds__(256, 4)
void attn_mfma(const u16* __restrict__ Qh, const u16* __restrict__ Kh,
               const u16* __restrict__ Vt, u16* __restrict__ AO) {
    __shared__ u16 Ks[64 * 64];
    __shared__ u16 Vs[64 * 64];
    __shared__ u16 Ps[4][16 * 72];

    const int t = threadIdx.x, lane = t & 63, w = t >> 6;

    const int orig = blockIdx.x;
    const int xcd = orig & 7, slot = orig >> 3;
    const int head_lin = xcd * 16 + (slot >> 4);
    const int qt = slot & 15;
    const int b = head_lin >> 4, h = head_lin & 15;
    const size_t head = (size_t)head_lin;

    const char* Qg = (const char*)(Qh + head * 1024 * 64) + qt * 64 * 128;
    const char* Kg = (const char*)(Kh + head * 1024 * 64);
    const char* Vg = (const char*)(Vt + head * 64 * 1024);
    char* KsC = (char*)Ks;
    char* VsC = (char*)Vs;
    char* PsC = (char*)(&Ps[w][0]);

    const int l15 = lane & 15;
    const int g16 = (lane >> 4) << 4;
    const int g8  = (lane >> 4) << 3;

    // stage K/V tile 0 (gload_lds, pre-swizzled source, linear LDS dest)
    #pragma unroll
    for (int i = 0; i < 2; i++) {
        int c = (w * 2 + i) * 64 + lane;
        int row = c >> 3, colb = (c & 7) * 16;
        int soff = colb ^ ((row & 7) << 4);
        GLDS16(Kg + row * 128 + soff, KsC + (w * 2 + i) * 1024);
        GLDS16(Vg + row * 2048 + soff, VsC + (w * 2 + i) * 1024);
    }

    // Q fragments from global (row-major [64 q][64 d], 128B rows)
    const int qrow = w * 16 + l15;
    bf16x8 qf[2];
    #pragma unroll
    for (int kk = 0; kk < 2; kk++)
        qf[kk] = *(const bf16x8*)(Qg + qrow * 128 + kk * 64 + g16);

    int ksrcoff[2], kdst[2], vsrcoff[2], vdst[2];
    #pragma unroll
    for (int i = 0; i < 2; i++) {
        int c = i * 256 + t;
        int row = c >> 3, colb = (c & 7) * 16;
        ksrcoff[i] = c * 16;
        kdst[i]    = row * 128 + (colb ^ ((row & 7) << 4));
        vsrcoff[i] = row * 2048 + colb;
        vdst[i]    = row * 128 + (colb ^ ((row & 7) << 4));
    }

    float lp = 0.f;                     // partial softmax denom for q = l15
    f32x4 acc_o[4];
    #pragma unroll
    for (int i = 0; i < 4; i++) acc_o[i] = f32x4{0.f, 0.f, 0.f, 0.f};

    __syncthreads();

    for (int kt = 0; kt < 16; kt++) {
        // T14 issue-early: next tile's K/V -> regs
        u16x8 kst[2], vst[2];
        if (kt < 15) {
            const char* ks = Kg + (kt + 1) * 8192;
            const char* vs = Vg + (kt + 1) * 128;
            #pragma unroll
            for (int i = 0; i < 2; i++) {
                kst[i] = *(const u16x8*)(ks + ksrcoff[i]);
                vst[i] = *(const u16x8*)(vs + vsrcoff[i]);
            }
        }

        // S^T = K Q^T (swapped operands): lane holds S^T[k=c*16+4g+reg][q=l15]
        f32x4 sacc[4];
        #pragma unroll
        for (int c = 0; c < 4; c++) sacc[c] = f32x4{0.f, 0.f, 0.f, 0.f};
        __builtin_amdgcn_s_setprio(1);
        #pragma unroll
        for (int kk = 0; kk < 2; kk++) {
            int csw = ((kk * 64) | g16) ^ ((l15 & 7) << 4);
            #pragma unroll
            for (int c = 0; c < 4; c++) {
                bf16x8 bk = *(const bf16x8*)(KsC + (c * 16 + l15) * 128 + csw);
                sacc[c] = __builtin_amdgcn_mfma_f32_16x16x32_bf16(bk, qf[kk], sacc[c], 0, 0, 0);
            }
        }
        __builtin_amdgcn_s_setprio(0);

        // P = 2^S (native v_exp_f32; Q pre-scaled by log2e); lane-partial l;
        // cvt_pk pack -> one short-typed b64 store per block (144B rows)
        {
            char* pb = PsC + l15 * 144 + g8;
            #pragma unroll
            for (int c = 0; c < 4; c++) {
                float p0 = __builtin_amdgcn_exp2f(sacc[c][0]);
                float p1 = __builtin_amdgcn_exp2f(sacc[c][1]);
                float p2 = __builtin_amdgcn_exp2f(sacc[c][2]);
                float p3 = __builtin_amdgcn_exp2f(sacc[c][3]);
                lp += (p0 + p1) + (p2 + p3);
                u32 w0, w1;
                asm("v_cvt_pk_bf16_f32 %0, %1, %2" : "=v"(w0) : "v"(p0), "v"(p1));
                asm("v_cvt_pk_bf16_f32 %0, %1, %2" : "=v"(w1) : "v"(p2), "v"(p3));
                u16x4 pk = __builtin_bit_cast(u16x4, u32x2{w0, w1});
                *(u16x4*)(pb + c * 32) = pk;
            }
        }
        // pin ordering: P writes complete before PV reads (compiler + HW)
        MEMFENCE;
        asm volatile("s_waitcnt lgkmcnt(0)" ::: "memory");
        __builtin_amdgcn_sched_barrier(0);

        // O += P @ V  (P read: row l15 at 144B stride)
        __builtin_amdgcn_s_setprio(1);
        #pragma unroll
        for (int kb = 0; kb < 2; kb++) {
            bf16x8 ap = *(const bf16x8*)(PsC + l15 * 144 + kb * 64 + g16);
            #pragma unroll
            for (int c2 = 0; c2 < 4; c2++) {
                int vrow = c2 * 16 + l15;
                int voff = vrow * 128 + (((kb << 6) | g16) ^ ((vrow & 7) << 4));
                bf16x8 bv = *(const bf16x8*)(VsC + voff);
                acc_o[c2] = __builtin_amdgcn_mfma_f32_16x16x32_bf16(ap, bv, acc_o[c2], 0, 0, 0);
            }
        }
        __builtin_amdgcn_s_setprio(0);

        __syncthreads();
        if (kt < 15) {
            #pragma unroll
            for (int i = 0; i < 2; i++) {
                *(u16x8*)(KsC + kdst[i]) = kst[i];
                *(u16x8*)(VsC + vdst[i]) = vst[i];
            }
            __syncthreads();
        }
    }

    // finalize l: reduce 4 lanes sharing q=l15, redistribute to O-fragment rows
    lp += __shfl_xor(lp, 16, 64);
    lp += __shfl_xor(lp, 32, 64);
    float linv[4];
    #pragma unroll
    for (int reg = 0; reg < 4; reg++)
        linv[reg] = 1.0f / __shfl(lp, ((lane >> 4) << 2) + reg, 64);

    // epilogue: AO [8192][1024] hi only
    #pragma unroll
    for (int c2 = 0; c2 < 4; c2++) {
        int col = h * 64 + c2 * 16 + l15;
        #pragma unroll
        for (int reg = 0; reg < 4; reg++) {
            int row = b * 1024 + qt * 64 + w * 16 + (lane >> 4) * 4 + reg;
            float v = acc_o[c2][reg] * linv[reg];
            AO[(size_t)row * 1024 + col] = f2bf(v);
        }
    }
}

// ---------------------------------------------------------------------------
extern "C" void kernel_launch(void* const* d_in, const int* in_sizes, int n_in,
                              void* d_out, int out_size, void* d_ws, size_t ws_size,
                              hipStream_t stream) {
    const float* x    = (const float*)d_in[0];   // [8,1024,1024]
    const float* Wqkv = (const float*)d_in[1];   // [1024,3072]
    const float* Wout = (const float*)d_in[2];   // [1024,1024]
    float* out = (float*)d_out;                  // [8,1024,1024] f32

    u16* xt    = (u16*)d_ws;                     // [8192][1024] hi
    u16* wqk   = xt + 8192ull * 1024;            // [2048][1024] hi
    u16* wv    = wqk + 2048ull * 1024;           // [1024][1024] hi
    u16* woutt = wv + 1024ull * 1024;            // [1024][1024] hi
    u16* Qh    = woutt + 1024ull * 1024;         // [128][1024][64] (x log2e/8)
    u16* Kh    = Qh + 128ull * 1024 * 64;        // [128][1024][64]
    u16* Vtr   = Kh + 128ull * 1024 * 64;        // [128][64][1024]
    u16* AO    = xt;                             // [8192][1024] hi (alias)

    convert_x<<<4096, 256, 0, stream>>>(x, xt);
    conv_w<<<dim3(96, 32), 256, 0, stream>>>(Wqkv, wqk, wv);
    conv_wout<<<dim3(32, 32), 256, 0, stream>>>(Wout, woutt);

    // Q,K projection: x_hi . W_hi, K'=1024, grid 256 blocks (exactly 1 round)
    gemm_qk_8ph<<<256, 512, 0, stream>>>(xt, wqk, Qh, Kh, 1024, 8);

    // V projection: hi-only K=1024
    gemm_bf16<2><<<512, 256, 0, stream>>>(
        xt, 1024, wv, 1024, 1024, nullptr, Vtr, 1024, 8);

    attn_mfma<<<2048, 256, 0, stream>>>(Qh, Kh, Vtr, AO);

    // output projection: AO_hi . W_hi, K=1024
    gemm_bf16<0><<<512, 256, 0, stream>>>(
        AO, 1024, woutt, 1024, 1024, out, nullptr, 1024, 8);
}

// Round 19
// 145.969 us; speedup vs baseline: 1.1166x; 1.0479x over previous
//
#include <hip/hip_runtime.h>
#include <math.h>

#define NH 16
#define HD 64

typedef unsigned short u16;
typedef unsigned int   u32;
using bf16x8 = __attribute__((ext_vector_type(8))) short;
using f32x4  = __attribute__((ext_vector_type(4))) float;
using u16x8  = __attribute__((ext_vector_type(8))) unsigned short;
using u16x4  = __attribute__((ext_vector_type(4))) unsigned short;
using u32x2  = __attribute__((ext_vector_type(2))) unsigned int;

__device__ __forceinline__ u16 f2bf(float x) {
    u32 u = __float_as_uint(x);
    u32 r = (u + 0x7FFFu + ((u >> 16) & 1u)) >> 16;
    return (u16)r;
}
__device__ __forceinline__ float bf2f(u16 h) { return __uint_as_float(((u32)h) << 16); }

#define GLDS16(src, dst) __builtin_amdgcn_global_load_lds( \
    (const __attribute__((address_space(1))) void*)(src),  \
    (__attribute__((address_space(3))) void*)(dst), 16, 0, 0)

#define LDS_OFF(p) ((u32)(uintptr_t)(__attribute__((address_space(3))) void*)(p))
#define DSREAD(d, a) asm volatile("ds_read_b128 %0, %1" : "=v"(d) : "v"(a))

#define MEMFENCE asm volatile("" ::: "memory")
#define BARMID { MEMFENCE; __builtin_amdgcn_s_barrier(); \
                 asm volatile("s_waitcnt lgkmcnt(0)" ::: "memory"); \
                 __builtin_amdgcn_sched_barrier(0); }
#define BAREND { MEMFENCE; __builtin_amdgcn_s_barrier(); MEMFENCE; }
#define VMW(n) asm volatile("s_waitcnt vmcnt(" #n ")" ::: "memory")

// ---------------------------------------------------------------------------
// x [8192][1024] f32 -> xt [8192][1024] bf16 (hi only)
__global__ __launch_bounds__(256) void convert_x(const float* __restrict__ x,
                                                 u16* __restrict__ xt) {
    int t = blockIdx.x * 256 + threadIdx.x;
    int m = t >> 7;
    int k = (t & 127) * 8;
    const float4* src = (const float4*)(x + (size_t)m * 1024 + k);
    float4 v0 = src[0], v1 = src[1];
    float vs[8] = {v0.x, v0.y, v0.z, v0.w, v1.x, v1.y, v1.z, v1.w};
    u16x8 hv;
    #pragma unroll
    for (int j = 0; j < 8; j++) hv[j] = f2bf(vs[j]);
    *(u16x8*)(xt + (size_t)m * 1024 + k) = hv;
}

// ---------------------------------------------------------------------------
// Wqkv [1024][3072] f32 -> transposed hi:
//   cols 0..2047   (Q,K): wqk [2048][1024]
//   cols 2048..3071 (V) : wv  [1024][1024]
__global__ __launch_bounds__(256) void conv_w(const float* __restrict__ W,
                                              u16* __restrict__ wqk,
                                              u16* __restrict__ wv) {
    __shared__ float Ts[32][33];
    const int N = 3072;
    int k0 = blockIdx.y * 32, n0 = blockIdx.x * 32;
    int t = threadIdx.x;
    int r = t >> 3, c4 = (t & 7) * 4;
    float4 v = *(const float4*)(W + (size_t)(k0 + r) * N + n0 + c4);
    Ts[r][c4] = v.x; Ts[r][c4 + 1] = v.y; Ts[r][c4 + 2] = v.z; Ts[r][c4 + 3] = v.w;
    __syncthreads();
    int nl = t >> 3, kl = (t & 7) * 4;
    u16x4 hv;
    #pragma unroll
    for (int j = 0; j < 4; j++) hv[j] = f2bf(Ts[kl + j][nl]);
    int col = n0 + nl;
    if (col < 2048) {
        *(u16x4*)&wqk[(size_t)col * 1024 + k0 + kl] = hv;
    } else {
        *(u16x4*)&wv[(size_t)(col - 2048) * 1024 + k0 + kl] = hv;
    }
}

// ---------------------------------------------------------------------------
// Wout [1024][1024] f32 -> Wt [1024][1024] bf16 hi (transposed)
__global__ __launch_bounds__(256) void conv_wout(const float* __restrict__ W,
                                                 u16* __restrict__ Wt) {
    __shared__ float Ts[32][33];
    const int N = 1024;
    int k0 = blockIdx.y * 32, n0 = blockIdx.x * 32;
    int t = threadIdx.x;
    int r = t >> 3, c4 = (t & 7) * 4;
    float4 v = *(const float4*)(W + (size_t)(k0 + r) * N + n0 + c4);
    Ts[r][c4] = v.x; Ts[r][c4 + 1] = v.y; Ts[r][c4 + 2] = v.z; Ts[r][c4 + 3] = v.w;
    __syncthreads();
    int nl = t >> 3, kl = (t & 7) * 4;
    u16x4 hv;
    #pragma unroll
    for (int j = 0; j < 4; j++) hv[j] = f2bf(Ts[kl + j][nl]);
    *(u16x4*)&Wt[(size_t)(n0 + nl) * 1024 + k0 + kl] = hv;
}

// ---------------------------------------------------------------------------
// 256x256 8-phase GEMM: Q,K projection (N=2048 -> grid exactly 256, Kp=1024).
// Epilogue: Q pre-scaled by (1/8)*log2(e) for exp2-based softmax; K plain.
__global__ __launch_bounds__(512, 2)
void gemm_qk_8ph(const u16* __restrict__ A, const u16* __restrict__ Bt,
                 u16* __restrict__ Qh, u16* __restrict__ Kh,
                 int Kp, int nbx) {
    __shared__ char LDS[131072];
    char* ldsA = LDS;
    char* ldsB = LDS + 65536;
    const u32 ldsAoff = LDS_OFF(ldsA);
    const u32 ldsBoff = ldsAoff + 65536;

    const int tid = threadIdx.x, lane = tid & 63, w = tid >> 6;
    const int wr = w >> 2, wc = w & 3;
    const int l15 = lane & 15;
    const int khb = (lane >> 4) << 4;
    const int lswz = (l15 & 7) << 4;
    const int Kp2 = Kp * 2;

    const int cpx = (int)gridDim.x >> 3;
    const int wg  = ((int)blockIdx.x & 7) * cpx + ((int)blockIdx.x >> 3);
    const int m0 = (wg / nbx) * 256, n0 = (wg % nbx) * 256;

    const int tp = tid >> 3;
    const int sw = ((tid & 7) * 16) ^ ((tp & 7) << 4);
    const int nA = ((tp >> 5) << 6) + (tp & 31);

    const char* Agb = (const char*)A  + (size_t)m0 * Kp2;
    const char* Bgb = (const char*)Bt + (size_t)n0 * Kp2;

#define STAGE_A(t, h, buf) { \
    const char* s_ = Agb + (t) * 128 + ((h) * 64 + tp) * Kp2 + sw; \
    char* d_ = ldsA + (buf) * 32768 + (h) * 16384 + (w << 10); \
    GLDS16(s_, d_); GLDS16(s_ + (size_t)128 * Kp2, d_ + 8192); }
#define STAGE_B(t, h, buf) { \
    const char* s_ = Bgb + (t) * 128 + (nA + (h) * 32) * Kp2 + sw; \
    char* d_ = ldsB + (buf) * 32768 + (h) * 16384 + (w << 10); \
    GLDS16(s_, d_); GLDS16(s_ + (size_t)128 * Kp2, d_ + 8192); }

    bf16x8 Af[4][2], Bf[2][2];

#define LOADA(buf, mh) { \
    _Pragma("unroll") \
    for (int mi = 0; mi < 4; ++mi) { \
        u32 rb_ = ldsAoff + (buf) * 32768 + (mh) * 16384 \
                + (u32)((wr * 64 + mi * 16 + l15) * 128); \
        DSREAD(Af[mi][0], rb_ + (u32)((khb) ^ lswz)); \
        DSREAD(Af[mi][1], rb_ + (u32)((64 + khb) ^ lswz)); \
    } }
#define LOADB(buf, nh) { \
    _Pragma("unroll") \
    for (int ni = 0; ni < 2; ++ni) { \
        u32 rb_ = ldsBoff + (buf) * 32768 + (nh) * 16384 \
                + (u32)((wc * 32 + ni * 16 + l15) * 128); \
        DSREAD(Bf[ni][0], rb_ + (u32)((khb) ^ lswz)); \
        DSREAD(Bf[ni][1], rb_ + (u32)((64 + khb) ^ lswz)); \
    } }
#define MM(mh, nh) { \
    __builtin_amdgcn_s_setprio(1); \
    _Pragma("unroll") \
    for (int kk = 0; kk < 2; ++kk) \
        _Pragma("unroll") \
        for (int mi = 0; mi < 4; ++mi) \
            _Pragma("unroll") \
            for (int ni = 0; ni < 2; ++ni) \
                acc[(mh) * 4 + mi][(nh) * 2 + ni] = \
                    __builtin_amdgcn_mfma_f32_16x16x32_bf16( \
                        Af[mi][kk], Bf[ni][kk], acc[(mh) * 4 + mi][(nh) * 2 + ni], 0, 0, 0); \
    __builtin_amdgcn_s_setprio(0); }

    f32x4 acc[8][4];
    #pragma unroll
    for (int i = 0; i < 8; i++)
        #pragma unroll
        for (int j = 0; j < 4; j++)
            acc[i][j] = f32x4{0.f, 0.f, 0.f, 0.f};

    const int NT = Kp >> 6;
    const int NITER = NT / 2 - 1;

    STAGE_B(0, 0, 0); STAGE_A(0, 1, 0); STAGE_B(0, 1, 0); STAGE_A(0, 0, 0);
    STAGE_B(1, 0, 1); STAGE_A(1, 1, 1); STAGE_B(1, 1, 1);
    VMW(6);
    MEMFENCE; __builtin_amdgcn_s_barrier(); MEMFENCE;

    for (int it = 0; it < NITER; ++it) {
        const int t = 2 * it;
        LOADA(0, 0); LOADB(0, 0); STAGE_A(t + 1, 0, 1);
        BARMID; MM(0, 0); BAREND;
        LOADA(0, 1); STAGE_B(t + 2, 0, 0);
        BARMID; MM(1, 0); BAREND;
        LOADB(0, 1); STAGE_A(t + 2, 1, 0);
        BARMID; MM(1, 1); BAREND;
        LOADA(0, 0); STAGE_B(t + 2, 1, 0); VMW(6);
        BARMID; MM(0, 1); BAREND;
        LOADA(1, 0); LOADB(1, 0); STAGE_A(t + 2, 0, 0);
        BARMID; MM(0, 0); BAREND;
        LOADA(1, 1); STAGE_B(t + 3, 0, 1);
        BARMID; MM(1, 0); BAREND;
        LOADB(1, 1); STAGE_A(t + 3, 1, 1);
        BARMID; MM(1, 1); BAREND;
        LOADA(1, 0); STAGE_B(t + 3, 1, 1); VMW(6);
        BARMID; MM(0, 1); BAREND;
    }

    LOADA(0, 0); LOADB(0, 0); STAGE_A(NT - 1, 0, 1);
    BARMID; MM(0, 0); BAREND;
    LOADA(0, 1);
    BARMID; MM(1, 0); BAREND;
    LOADB(0, 1);
    BARMID; MM(1, 1); BAREND;
    LOADA(0, 0); VMW(0);
    BARMID; MM(0, 1); BAREND;
    LOADA(1, 0); LOADB(1, 0);
    BARMID; MM(0, 0); BAREND;
    LOADA(1, 1);
    BARMID; MM(1, 0); BAREND;
    LOADB(1, 1);
    BARMID; MM(1, 1); BAREND;
    LOADA(1, 0);
    BARMID; MM(0, 1); BAREND;

    const int sel = n0 >> 10;   // 0 = Q, 1 = K
    u16* dst = (sel == 0) ? Qh : Kh;
    // Q scale folds 1/sqrt(64) and log2(e) (softmax uses exp2)
    const float sc = (sel == 0) ? 0.125f * 1.4426950408889634f : 1.0f;
    #pragma unroll
    for (int mh = 0; mh < 2; ++mh)
        #pragma unroll
        for (int mi = 0; mi < 4; ++mi)
            #pragma unroll
            for (int nh = 0; nh < 2; ++nh)
                #pragma unroll
                for (int ni = 0; ni < 2; ++ni) {
                    f32x4 a = acc[mh * 4 + mi][nh * 2 + ni];
                    int col = n0 + wc * 64 + nh * 32 + ni * 16 + l15;
                    int within = col & 1023;
                    int hh = within >> 6, d = within & 63;
                    int rowb = m0 + wr * 128 + mh * 64 + mi * 16 + (lane >> 4) * 4;
                    int bb = rowb >> 10, n = rowb & 1023;
                    size_t hn = (size_t)(bb * NH + hh) * 1024 + n;
                    #pragma unroll
                    for (int reg = 0; reg < 4; reg++)
                        dst[(hn + reg) * 64 + d] = f2bf(a[reg] * sc);
                }
#undef STAGE_A
#undef STAGE_B
#undef LOADA
#undef LOADB
#undef MM
}

// ---------------------------------------------------------------------------
// 128x128 bf16 GEMM, m97 structure, strided A/B (lda/ldb in elements).
// MODE 0: C f32 [M][N].  MODE 2: V write transposed -> Vtr [head][64][1024].
template<int MODE>
__global__ __launch_bounds__(256, 2)
void gemm_bf16(const u16* __restrict__ A, int lda,
               const u16* __restrict__ Bt, int ldb, int Kloop,
               float* __restrict__ C, u16* __restrict__ Vtr, int N, int nbx) {
    __shared__ u16 As[128 * 64];
    __shared__ u16 Bs[128 * 64];
    const char* AsC = (const char*)As;
    const char* BsC = (const char*)Bs;

    const int t = threadIdx.x;
    const int lane = t & 63, w = t >> 6;

    const int cpx = (int)gridDim.x >> 3;
    const int wg  = (blockIdx.x & 7) * cpx + (blockIdx.x >> 3);
    const int m0 = (wg / nbx) * 128, n0 = (wg % nbx) * 128;

    const int l15 = lane & 15;
    const int g16 = (lane >> 4) << 4;
    const int swz = (l15 & 7) << 4;

    const char* srcA[4];
    const char* srcB[4];
    char* dstA[4];
    char* dstB[4];
    #pragma unroll
    for (int i = 0; i < 4; i++) {
        int s = (w * 4 + i) * 64 + lane;
        int row  = (s * 16) >> 7;
        int colb = (s * 16) & 127;
        int scol = colb ^ ((row & 7) << 4);
        srcA[i] = (const char*)A  + ((size_t)(m0 + row) * lda) * 2 + scol;
        srcB[i] = (const char*)Bt + ((size_t)(n0 + row) * ldb) * 2 + scol;
        dstA[i] = (char*)As + (w * 4 + i) * 1024;
        dstB[i] = (char*)Bs + (w * 4 + i) * 1024;
    }

    const int wm = (w >> 1) * 64, wn = (w & 1) * 64;
    int rA[4], rB[4];
    #pragma unroll
    for (int i = 0; i < 4; i++) {
        rA[i] = (wm + i * 16 + l15) * 128;
        rB[i] = (wn + i * 16 + l15) * 128;
    }

    f32x4 acc[4][4];
    #pragma unroll
    for (int i = 0; i < 4; i++)
        #pragma unroll
        for (int j = 0; j < 4; j++)
            acc[i][j] = f32x4{0.f, 0.f, 0.f, 0.f};

    for (int k0 = 0; k0 < Kloop; k0 += 64) {
        __syncthreads();
        #pragma unroll
        for (int i = 0; i < 4; i++) {
            GLDS16(srcA[i], dstA[i]);
            GLDS16(srcB[i], dstB[i]);
            srcA[i] += 128;
            srcB[i] += 128;
        }
        __syncthreads();
        #pragma unroll
        for (int kb = 0; kb < 2; kb++) {
            const int csw = ((kb << 6) | g16) ^ swz;
            bf16x8 af[4], bfr[4];
            #pragma unroll
            for (int mi = 0; mi < 4; mi++) af[mi]  = *(const bf16x8*)(AsC + rA[mi] + csw);
            #pragma unroll
            for (int ni = 0; ni < 4; ni++) bfr[ni] = *(const bf16x8*)(BsC + rB[ni] + csw);
            #pragma unroll
            for (int mi = 0; mi < 4; mi++)
                #pragma unroll
                for (int ni = 0; ni < 4; ni++)
                    acc[mi][ni] = __builtin_amdgcn_mfma_f32_16x16x32_bf16(
                        af[mi], bfr[ni], acc[mi][ni], 0, 0, 0);
        }
    }

    if (MODE == 0) {
        #pragma unroll
        for (int mi = 0; mi < 4; mi++) {
            int rowb = m0 + wm + mi * 16 + (lane >> 4) * 4;
            #pragma unroll
            for (int ni = 0; ni < 4; ni++) {
                int col = n0 + wn + ni * 16 + l15;
                #pragma unroll
                for (int reg = 0; reg < 4; reg++)
                    C[(size_t)(rowb + reg) * N + col] = acc[mi][ni][reg];
            }
        }
    } else {
        // V: write transposed [head][d][key]
        #pragma unroll
        for (int ni = 0; ni < 4; ni++) {
            int col = n0 + wn + ni * 16 + l15;      // 0..1023
            int hh = col >> 6, d = col & 63;
            #pragma unroll
            for (int mi = 0; mi < 4; mi++) {
                int rowb = m0 + wm + mi * 16 + (lane >> 4) * 4;
                int bb = rowb >> 10, n = rowb & 1023;
                u16x4 vv;
                #pragma unroll
                for (int reg = 0; reg < 4; reg++)
                    vv[reg] = f2bf(acc[mi][ni][reg]);
                *(u16x4*)&Vtr[((size_t)(bb * NH + hh) * 64 + d) * 1024 + n] = vv;
            }
        }
    }
}

// ---------------------------------------------------------------------------
// Flash attention, swapped-QK^T (T12), QBLK=128: each block computes 128
// q-rows against shared K/V tiles (halves staging + barriers per unit work).
// Wave w owns q sub-tiles {w*16..+15} and {64+w*16..+15}. QK^T/softmax run
// per sub-tile (register pressure); PV fused (one bv feeds both). Native
// exp2 softmax (Q pre-scaled by 0.125*log2e). Grid 1024, 4 blocks/CU.
__global__ __launch_bounds__(256, 4)
void attn_mfma(const u16* __restrict__ Qh, const u16* __restrict__ Kh,
               const u16* __restrict__ Vt, u16* __restrict__ AO) {
    __shared__ u16 Ks[64 * 64];
    __shared__ u16 Vs[64 * 64];
    __shared__ u16 Ps[4][2 * 16 * 72];

    const int t = threadIdx.x, lane = t & 63, w = t >> 6;

    const int orig = blockIdx.x;
    const int xcd = orig & 7, slot = orig >> 3;        // slot 0..127
    const int head_lin = xcd * 16 + (slot >> 3);       // 0..127
    const int qt = slot & 7;                           // 8 q-tiles of 128
    const int b = head_lin >> 4, h = head_lin & 15;
    const size_t head = (size_t)head_lin;

    const char* Qg = (const char*)(Qh + head * 1024 * 64) + qt * 128 * 128;
    const char* Kg = (const char*)(Kh + head * 1024 * 64);
    const char* Vg = (const char*)(Vt + head * 64 * 1024);
    char* KsC = (char*)Ks;
    char* VsC = (char*)Vs;
    char* PsC = (char*)(&Ps[w][0]);

    const int l15 = lane & 15;
    const int g16 = (lane >> 4) << 4;
    const int g8  = (lane >> 4) << 3;

    // stage K/V tile 0 (gload_lds, pre-swizzled source, linear LDS dest)
    #pragma unroll
    for (int i = 0; i < 2; i++) {
        int c = (w * 2 + i) * 64 + lane;
        int row = c >> 3, colb = (c & 7) * 16;
        int soff = colb ^ ((row & 7) << 4);
        GLDS16(Kg + row * 128 + soff, KsC + (w * 2 + i) * 1024);
        GLDS16(Vg + row * 2048 + soff, VsC + (w * 2 + i) * 1024);
    }

    // Q fragments from global: 2 sub-tiles x 2 d-halves
    const int qrow = w * 16 + l15;
    bf16x8 qf[2][2];
    #pragma unroll
    for (int qs = 0; qs < 2; qs++)
        #pragma unroll
        for (int kk = 0; kk < 2; kk++)
            qf[qs][kk] = *(const bf16x8*)(Qg + (qs * 64 + qrow) * 128 + kk * 64 + g16);

    int ksrcoff[2], kdst[2], vsrcoff[2], vdst[2];
    #pragma unroll
    for (int i = 0; i < 2; i++) {
        int c = i * 256 + t;
        int row = c >> 3, colb = (c & 7) * 16;
        ksrcoff[i] = c * 16;
        kdst[i]    = row * 128 + (colb ^ ((row & 7) << 4));
        vsrcoff[i] = row * 2048 + colb;
        vdst[i]    = row * 128 + (colb ^ ((row & 7) << 4));
    }

    float lp[2] = {0.f, 0.f};           // partial softmax denom per sub-tile
    f32x4 acc_o[2][4];
    #pragma unroll
    for (int qs = 0; qs < 2; qs++)
        #pragma unroll
        for (int i = 0; i < 4; i++) acc_o[qs][i] = f32x4{0.f, 0.f, 0.f, 0.f};

    __syncthreads();

    for (int kt = 0; kt < 16; kt++) {
        // T14 issue-early: next tile's K/V -> regs
        u16x8 kst[2], vst[2];
        if (kt < 15) {
            const char* ks = Kg + (kt + 1) * 8192;
            const char* vs = Vg + (kt + 1) * 128;
            #pragma unroll
            for (int i = 0; i < 2; i++) {
                kst[i] = *(const u16x8*)(ks + ksrcoff[i]);
                vst[i] = *(const u16x8*)(vs + vsrcoff[i]);
            }
        }

        // per sub-tile: S^T = K Q^T, then P = 2^S -> LDS
        #pragma unroll
        for (int qs = 0; qs < 2; qs++) {
            f32x4 sacc[4];
            #pragma unroll
            for (int c = 0; c < 4; c++) sacc[c] = f32x4{0.f, 0.f, 0.f, 0.f};
            __builtin_amdgcn_s_setprio(1);
            #pragma unroll
            for (int kk = 0; kk < 2; kk++) {
                int csw = ((kk * 64) | g16) ^ ((l15 & 7) << 4);
                #pragma unroll
                for (int c = 0; c < 4; c++) {
                    bf16x8 bk = *(const bf16x8*)(KsC + (c * 16 + l15) * 128 + csw);
                    sacc[c] = __builtin_amdgcn_mfma_f32_16x16x32_bf16(bk, qf[qs][kk], sacc[c], 0, 0, 0);
                }
            }
            __builtin_amdgcn_s_setprio(0);

            char* pb = PsC + qs * 2304 + l15 * 144 + g8;
            #pragma unroll
            for (int c = 0; c < 4; c++) {
                float p0 = __builtin_amdgcn_exp2f(sacc[c][0]);
                float p1 = __builtin_amdgcn_exp2f(sacc[c][1]);
                float p2 = __builtin_amdgcn_exp2f(sacc[c][2]);
                float p3 = __builtin_amdgcn_exp2f(sacc[c][3]);
                lp[qs] += (p0 + p1) + (p2 + p3);
                u32 w0, w1;
                asm("v_cvt_pk_bf16_f32 %0, %1, %2" : "=v"(w0) : "v"(p0), "v"(p1));
                asm("v_cvt_pk_bf16_f32 %0, %1, %2" : "=v"(w1) : "v"(p2), "v"(p3));
                u16x4 pk = __builtin_bit_cast(u16x4, u32x2{w0, w1});
                *(u16x4*)(pb + c * 32) = pk;
            }
        }
        // pin ordering: P writes complete before PV reads (compiler + HW)
        MEMFENCE;
        asm volatile("s_waitcnt lgkmcnt(0)" ::: "memory");
        __builtin_amdgcn_sched_barrier(0);

        // O += P @ V: one bv load feeds both sub-tiles' MFMAs
        __builtin_amdgcn_s_setprio(1);
        #pragma unroll
        for (int kb = 0; kb < 2; kb++) {
            bf16x8 ap0 = *(const bf16x8*)(PsC + l15 * 144 + kb * 64 + g16);
            bf16x8 ap1 = *(const bf16x8*)(PsC + 2304 + l15 * 144 + kb * 64 + g16);
            #pragma unroll
            for (int c2 = 0; c2 < 4; c2++) {
                int vrow = c2 * 16 + l15;
                int voff = vrow * 128 + (((kb << 6) | g16) ^ ((vrow & 7) << 4));
                bf16x8 bv = *(const bf16x8*)(VsC + voff);
                acc_o[0][c2] = __builtin_amdgcn_mfma_f32_16x16x32_bf16(ap0, bv, acc_o[0][c2], 0, 0, 0);
                acc_o[1][c2] = __builtin_amdgcn_mfma_f32_16x16x32_bf16(ap1, bv, acc_o[1][c2], 0, 0, 0);
            }
        }
        __builtin_amdgcn_s_setprio(0);

        __syncthreads();
        if (kt < 15) {
            #pragma unroll
            for (int i = 0; i < 2; i++) {
                *(u16x8*)(KsC + kdst[i]) = kst[i];
                *(u16x8*)(VsC + vdst[i]) = vst[i];
            }
            __syncthreads();
        }
    }

    // finalize l per sub-tile; epilogue: AO [8192][1024] hi only
    #pragma unroll
    for (int qs = 0; qs < 2; qs++) {
        float l = lp[qs];
        l += __shfl_xor(l, 16, 64);
        l += __shfl_xor(l, 32, 64);
        float linv[4];
        #pragma unroll
        for (int reg = 0; reg < 4; reg++)
            linv[reg] = 1.0f / __shfl(l, ((lane >> 4) << 2) + reg, 64);

        #pragma unroll
        for (int c2 = 0; c2 < 4; c2++) {
            int col = h * 64 + c2 * 16 + l15;
            #pragma unroll
            for (int reg = 0; reg < 4; reg++) {
                int row = b * 1024 + qt * 128 + qs * 64 + w * 16 + (lane >> 4) * 4 + reg;
                float v = acc_o[qs][c2][reg] * linv[reg];
                AO[(size_t)row * 1024 + col] = f2bf(v);
            }
        }
    }
}

// ---------------------------------------------------------------------------
extern "C" void kernel_launch(void* const* d_in, const int* in_sizes, int n_in,
                              void* d_out, int out_size, void* d_ws, size_t ws_size,
                              hipStream_t stream) {
    const float* x    = (const float*)d_in[0];   // [8,1024,1024]
    const float* Wqkv = (const float*)d_in[1];   // [1024,3072]
    const float* Wout = (const float*)d_in[2];   // [1024,1024]
    float* out = (float*)d_out;                  // [8,1024,1024] f32

    u16* xt    = (u16*)d_ws;                     // [8192][1024] hi
    u16* wqk   = xt + 8192ull * 1024;            // [2048][1024] hi
    u16* wv    = wqk + 2048ull * 1024;           // [1024][1024] hi
    u16* woutt = wv + 1024ull * 1024;            // [1024][1024] hi
    u16* Qh    = woutt + 1024ull * 1024;         // [128][1024][64] (x log2e/8)
    u16* Kh    = Qh + 128ull * 1024 * 64;        // [128][1024][64]
    u16* Vtr   = Kh + 128ull * 1024 * 64;        // [128][64][1024]
    u16* AO    = xt;                             // [8192][1024] hi (alias)

    convert_x<<<4096, 256, 0, stream>>>(x, xt);
    conv_w<<<dim3(96, 32), 256, 0, stream>>>(Wqkv, wqk, wv);
    conv_wout<<<dim3(32, 32), 256, 0, stream>>>(Wout, woutt);

    // Q,K projection: x_hi . W_hi, K'=1024, grid 256 blocks (exactly 1 round)
    gemm_qk_8ph<<<256, 512, 0, stream>>>(xt, wqk, Qh, Kh, 1024, 8);

    // V projection: hi-only K=1024
    gemm_bf16<2><<<512, 256, 0, stream>>>(
        xt, 1024, wv, 1024, 1024, nullptr, Vtr, 1024, 8);

    attn_mfma<<<1024, 256, 0, stream>>>(Qh, Kh, Vtr, AO);

    // output projection: AO_hi . W_hi, K=1024
    gemm_bf16<0><<<512, 256, 0, stream>>>(
        AO, 1024, woutt, 1024, 1024, out, nullptr, 1024, 8);
}